// Round 2
// baseline (902.396 us; speedup 1.0000x reference)
//
#include <hip/hip_runtime.h>
#include <hip/hip_bf16.h>
#include <type_traits>

#define NN   8000
#define NE   64000
#define NE2  72000   // edges + self loops
#define NH   8
#define OC   512
#define HC   4096    // NH*OC
#define KIN  128
#define NOUT 512
#define NEG_SLOPE 0.2f

using bf16 = __hip_bfloat16;

static __device__ __forceinline__ float b2f(bf16 v){ return __bfloat162float(v); }
static __device__ __forceinline__ float ldf(const float* p){ return *p; }
static __device__ __forceinline__ float ldf(const bf16* p){ return b2f(*p); }
static __device__ __forceinline__ unsigned short f2bu(float f){
    bf16 b = __float2bfloat16(f);
    return *reinterpret_cast<unsigned short*>(&b);
}

// ---------------- init: zero counters, b_eff = b_lin ----------------
__global__ void k_init(int* counts, int* cursors, float* b_eff, const float* __restrict__ b_lin){
    int i = blockIdx.x*blockDim.x + threadIdx.x;
    if (i < NN){ counts[i] = 0; cursors[i] = 0; }
    if (i < NOUT){ b_eff[i] = b_lin[i]; }
}

// ---------------- generic GEMM: C[M,N] = A[M,K]@B[K,N] (+bias) ----------------
// tile 128x64, BK=32, 256 threads, 8x4 micro-tile. M may be non-multiple of 128.
template<typename TA, typename TB, typename TC, bool BIAS>
__global__ __launch_bounds__(256) void k_gemm(
    const TA* __restrict__ A, const TB* __restrict__ B,
    const float* __restrict__ bias, TC* __restrict__ Cout,
    int M, int N, int K)
{
    constexpr int BM=128, BN=64, BK=32;
    __shared__ __align__(16) float sA[BK][BM+4];   // row = 132 floats = 528B (16B-mult)
    __shared__ __align__(16) float sB[BK][BN+4];   // row = 68 floats = 272B (16B-mult)
    const int tid = threadIdx.x;
    const int m0 = blockIdx.x * BM;
    const int n0 = blockIdx.y * BN;
    const int tx = tid & 15;     // col group: 4 cols
    const int ty = tid >> 4;     // row group: 8 rows
    float acc[8][4];
    #pragma unroll
    for (int i=0;i<8;++i)
        #pragma unroll
        for (int j=0;j<4;++j) acc[i][j] = 0.f;

    for (int k0=0; k0<K; k0+=BK){
        // stage A: BM x BK (transposed into sA[k][m]); 16 elems/thread
        {
            int m  = tid >> 1;
            int kk = (tid & 1) * 16;
            int row = m0 + m;
            if (row < M){
                const TA* ap = A + (size_t)row*K + k0 + kk;
                #pragma unroll
                for (int u=0;u<16;++u) sA[kk+u][m] = ldf(ap+u);
            } else {
                #pragma unroll
                for (int u=0;u<16;++u) sA[kk+u][m] = 0.f;
            }
        }
        // stage B: BK x BN; 8 elems/thread
        {
            int kk = tid >> 3;
            int n  = (tid & 7) * 8;
            const TB* bp = B + (size_t)(k0+kk)*N + n0 + n;
            #pragma unroll
            for (int u=0;u<8;++u) sB[kk][n+u] = ldf(bp+u);
        }
        __syncthreads();
        #pragma unroll
        for (int k=0;k<BK;++k){
            float ar[8], br[4];
            *(float4*)&ar[0] = *(const float4*)&sA[k][ty*8];
            *(float4*)&ar[4] = *(const float4*)&sA[k][ty*8+4];
            *(float4*)&br[0] = *(const float4*)&sB[k][tx*4];
            #pragma unroll
            for (int i=0;i<8;++i)
                #pragma unroll
                for (int j=0;j<4;++j)
                    acc[i][j] = fmaf(ar[i], br[j], acc[i][j]);
        }
        __syncthreads();
    }
    #pragma unroll
    for (int i=0;i<8;++i){
        int row = m0 + ty*8 + i;
        if (row < M){
            int col = n0 + tx*4;
            float v0 = acc[i][0] + (BIAS ? bias[col+0] : 0.f);
            float v1 = acc[i][1] + (BIAS ? bias[col+1] : 0.f);
            float v2 = acc[i][2] + (BIAS ? bias[col+2] : 0.f);
            float v3 = acc[i][3] + (BIAS ? bias[col+3] : 0.f);
            if constexpr (std::is_same<TC, bf16>::value){
                ushort4 pk;
                pk.x = f2bu(v0); pk.y = f2bu(v1); pk.z = f2bu(v2); pk.w = f2bu(v3);
                *reinterpret_cast<ushort4*>(Cout + (size_t)row*N + col) = pk;
            } else {
                float4 pk; pk.x=v0; pk.y=v1; pk.z=v2; pk.w=v3;
                *reinterpret_cast<float4*>(Cout + (size_t)row*N + col) = pk;
            }
        }
    }
}

// ---------------- per-node attention logits: a_src/a_dst [NN,NH] ----------------
__global__ __launch_bounds__(512) void k_attn(const bf16* __restrict__ h,
    const float* __restrict__ att_src, const float* __restrict__ att_dst,
    float* __restrict__ a_src, float* __restrict__ a_dst)
{
    int n = blockIdx.x;
    int w = threadIdx.x >> 6;    // head (8 waves/block)
    int lane = threadIdx.x & 63;
    const bf16*  hp = h + (size_t)n*HC + w*OC;
    const float* as = att_src + w*OC;
    const float* ad = att_dst + w*OC;
    float sa = 0.f, sd = 0.f;
    for (int c=lane; c<OC; c+=64){
        float hv = b2f(hp[c]);
        sa += hv * as[c];
        sd += hv * ad[c];
    }
    #pragma unroll
    for (int off=32; off; off>>=1){
        sa += __shfl_down(sa, off);
        sd += __shfl_down(sd, off);
    }
    if (lane == 0){
        a_src[n*NH + w] = sa;
        a_dst[n*NH + w] = sd;
    }
}

// ---------------- CSR build ----------------
__global__ void k_count(const int* __restrict__ eidx, int* __restrict__ counts){
    int e = blockIdx.x*blockDim.x + threadIdx.x;
    if (e >= NE2) return;
    int dst = (e < NE) ? eidx[NE + e] : (e - NE);
    atomicAdd(&counts[dst], 1);
}

__global__ __launch_bounds__(256) void k_scan(const int* __restrict__ counts, int* __restrict__ offsets){
    __shared__ int part[256];
    int t = threadIdx.x;
    int base = t*32;
    int s = 0;
    for (int u=0;u<32;++u){ int i = base+u; if (i<NN) s += counts[i]; }
    part[t] = s;
    __syncthreads();
    for (int off=1; off<256; off<<=1){
        int v = (t>=off) ? part[t-off] : 0;
        __syncthreads();
        part[t] += v;
        __syncthreads();
    }
    int run = (t==0) ? 0 : part[t-1];
    for (int u=0;u<32;++u){
        int i = base+u;
        if (i<NN){ offsets[i] = run; run += counts[i]; }
    }
    if (t == 255) offsets[NN] = run;   // == NE2
}

__global__ void k_fill(const int* __restrict__ eidx, const int* __restrict__ offsets,
                       int* __restrict__ cursors, int* __restrict__ esrc){
    int e = blockIdx.x*blockDim.x + threadIdx.x;
    if (e >= NE2) return;
    int src, dst;
    if (e < NE){ src = eidx[e]; dst = eidx[NE+e]; } else { src = dst = e - NE; }
    int pos = atomicAdd(&cursors[dst], 1);
    esrc[offsets[dst] + pos] = src;
}

// ---------------- per (node,head): segment max + 1/(sum exp) ----------------
__global__ void k_maxsum(const int* __restrict__ offsets, const int* __restrict__ esrc,
    const float* __restrict__ a_src, const float* __restrict__ a_dst,
    float* __restrict__ nmax, float* __restrict__ ninv)
{
    int t = blockIdx.x*blockDim.x + threadIdx.x;
    if (t >= NN*NH) return;
    int i = t >> 3, hh = t & 7;
    float ad = a_dst[t];
    int s0 = offsets[i], s1 = offsets[i+1];
    float m = -1e30f;
    for (int s=s0; s<s1; ++s){
        float l = a_src[esrc[s]*NH + hh] + ad;
        l = l > 0.f ? l : NEG_SLOPE*l;
        m = fmaxf(m, l);
    }
    float sum = 0.f;
    for (int s=s0; s<s1; ++s){
        float l = a_src[esrc[s]*NH + hh] + ad;
        l = l > 0.f ? l : NEG_SLOPE*l;
        sum += expf(l - m);
    }
    nmax[t] = m;
    ninv[t] = 1.f / (sum + 1e-16f);
}

// ---------------- per node: weighted aggregation of h -> agg ----------------
__global__ __launch_bounds__(256) void k_agg(const int* __restrict__ offsets,
    const int* __restrict__ esrc, const float* __restrict__ a_src,
    const float* __restrict__ a_dst, const float* __restrict__ nmax,
    const float* __restrict__ ninv, const bf16* __restrict__ h,
    bf16* __restrict__ agg)
{
    __shared__ float adst_s[NH], m_s[NH], inv_s[NH];
    __shared__ int   src_s[32];
    __shared__ float w_s[32][NH];
    int i = blockIdx.x;
    int tid = threadIdx.x;
    if (tid < NH){
        adst_s[tid] = a_dst[i*NH+tid];
        m_s[tid]    = nmax[i*NH+tid];
        inv_s[tid]  = ninv[i*NH+tid];
    }
    __syncthreads();
    float acc[16];
    #pragma unroll
    for (int j=0;j<16;++j) acc[j] = 0.f;
    int s0 = offsets[i], s1 = offsets[i+1];
    for (int c0=s0; c0<s1; c0+=32){
        int cnt = min(32, s1-c0);
        if (tid < cnt) src_s[tid] = esrc[c0+tid];
        __syncthreads();
        {
            int e = tid >> 3, hh = tid & 7;
            if (e < cnt){
                float l = a_src[src_s[e]*NH + hh] + adst_s[hh];
                l = l > 0.f ? l : NEG_SLOPE*l;
                w_s[e][hh] = expf(l - m_s[hh]) * inv_s[hh];
            }
        }
        __syncthreads();
        for (int e=0; e<cnt; ++e){
            const bf16* hp = h + (size_t)src_s[e]*HC + tid;
            #pragma unroll
            for (int j=0;j<16;++j){
                // column c = tid + j*256 -> head = j>>1 (uniform per (e,j): LDS broadcast)
                acc[j] += w_s[e][j>>1] * b2f(hp[j*256]);
            }
        }
        __syncthreads();
    }
    bf16* op = agg + (size_t)i*HC + tid;
    #pragma unroll
    for (int j=0;j<16;++j) op[j*256] = __float2bfloat16(acc[j]);
}

// ---------------- b_eff += b_gat @ W_lin (b_eff preloaded with b_lin) ----------------
__global__ __launch_bounds__(512) void k_beff(const float* __restrict__ b_gat,
    const float* __restrict__ W_lin, float* __restrict__ b_eff)
{
    int c  = threadIdx.x;
    int kb = blockIdx.x;         // 8 blocks x 512 k
    float acc = 0.f;
    for (int k = kb*512; k < (kb+1)*512; ++k)
        acc += b_gat[k] * W_lin[(size_t)k*NOUT + c];
    atomicAdd(&b_eff[c], acc);
}

extern "C" void kernel_launch(void* const* d_in, const int* in_sizes, int n_in,
                              void* d_out, int out_size, void* d_ws, size_t ws_size,
                              hipStream_t stream)
{
    const float* x       = (const float*)d_in[0];
    const int*   eidx    = (const int*)  d_in[1];
    const float* W_gat   = (const float*)d_in[2];
    const float* b_gat   = (const float*)d_in[3];
    const float* att_src = (const float*)d_in[4];
    const float* att_dst = (const float*)d_in[5];
    const float* W_lin   = (const float*)d_in[6];
    const float* b_lin   = (const float*)d_in[7];
    float* out = (float*)d_out;

    char* p = (char*)d_ws;
    auto alloc = [&](size_t bytes){ void* r = (void*)p; p += (bytes + 255) & ~(size_t)255; return r; };
    bf16*  h      = (bf16*) alloc((size_t)NN*HC*2);
    bf16*  agg    = (bf16*) alloc((size_t)NN*HC*2);
    float* a_src  = (float*)alloc((size_t)NN*NH*4);
    float* a_dst  = (float*)alloc((size_t)NN*NH*4);
    float* nmax   = (float*)alloc((size_t)NN*NH*4);
    float* ninv   = (float*)alloc((size_t)NN*NH*4);
    int*   offs   = (int*)  alloc((size_t)(NN+1)*4);
    int*   counts = (int*)  alloc((size_t)NN*4);
    int*   cursors= (int*)  alloc((size_t)NN*4);
    int*   esrc   = (int*)  alloc((size_t)NE2*4);
    float* b_eff  = (float*)alloc((size_t)NOUT*4);
    if ((size_t)(p - (char*)d_ws) > ws_size) return;  // ws too small: bail (no corruption)

    k_init<<<32, 256, 0, stream>>>(counts, cursors, b_eff, b_lin);
    k_gemm<float,float,bf16,false><<<dim3(63,64), 256, 0, stream>>>(x, W_gat, nullptr, h, NN, HC, KIN);
    k_attn<<<NN, 512, 0, stream>>>(h, att_src, att_dst, a_src, a_dst);
    k_count<<<(NE2+255)/256, 256, 0, stream>>>(eidx, counts);
    k_scan<<<1, 256, 0, stream>>>(counts, offs);
    k_fill<<<(NE2+255)/256, 256, 0, stream>>>(eidx, offs, cursors, esrc);
    k_maxsum<<<(NN*NH+255)/256, 256, 0, stream>>>(offs, esrc, a_src, a_dst, nmax, ninv);
    k_agg<<<NN, 256, 0, stream>>>(offs, esrc, a_src, a_dst, nmax, ninv, h, agg);
    k_beff<<<8, 512, 0, stream>>>(b_gat, W_lin, b_eff);
    k_gemm<bf16,float,float,true><<<dim3(63,8), 256, 0, stream>>>(agg, W_lin, b_eff, out, NN, NOUT, HC);
}

// Round 3
// 481.885 us; speedup vs baseline: 1.8726x; 1.8726x over previous
//
#include <hip/hip_runtime.h>
#include <hip/hip_bf16.h>
#include <type_traits>

#define NN   8000
#define NE   64000
#define NE2  72000   // edges + self loops
#define NH   8
#define OC   512
#define HC   4096    // NH*OC
#define KIN  128
#define NOUT 512
#define NEG_SLOPE 0.2f

using bf16 = __hip_bfloat16;
typedef float  f32x4  __attribute__((ext_vector_type(4)));
typedef __bf16 bf16x8 __attribute__((ext_vector_type(8)));

static __device__ __forceinline__ float b2f(bf16 v){ return __bfloat162float(v); }

static __device__ __forceinline__ void gld_lds16(const bf16* g, bf16* l){
    __builtin_amdgcn_global_load_lds(
        (const __attribute__((address_space(1))) unsigned int*)g,
        (__attribute__((address_space(3))) unsigned int*)l, 16, 0, 0);
}

// ---------------- init: zero counters, b_eff = b_lin ----------------
__global__ void k_init(int* counts, int* cursors, float* b_eff, const float* __restrict__ b_lin){
    int i = blockIdx.x*blockDim.x + threadIdx.x;
    if (i < NN){ counts[i] = 0; cursors[i] = 0; }
    if (i < NOUT){ b_eff[i] = b_lin[i]; }
}

// ---------------- fp32 -> bf16 convert (n divisible by 4) ----------------
__global__ void k_cvt(const float* __restrict__ in, bf16* __restrict__ out, int n4){
    int i = blockIdx.x*blockDim.x + threadIdx.x;
    if (i >= n4) return;
    float4 v = reinterpret_cast<const float4*>(in)[i];
    ushort4 o;
    bf16 b0 = __float2bfloat16(v.x), b1 = __float2bfloat16(v.y);
    bf16 b2 = __float2bfloat16(v.z), b3 = __float2bfloat16(v.w);
    o.x = *(unsigned short*)&b0; o.y = *(unsigned short*)&b1;
    o.z = *(unsigned short*)&b2; o.w = *(unsigned short*)&b3;
    reinterpret_cast<ushort4*>(out)[i] = o;
}

// ---------------- transpose+convert: in[K][N] fp32 -> out[N][K] bf16 ----------------
// K,N divisible by 32. grid (N/32, K/32), block 256.
__global__ __launch_bounds__(256) void k_tcvt(const float* __restrict__ in, bf16* __restrict__ out,
                                              int K, int N){
    __shared__ float t[32][33];
    int tx = threadIdx.x & 31, ty = threadIdx.x >> 5;   // 32 x 8
    int n0 = blockIdx.x*32, k0 = blockIdx.y*32;
    #pragma unroll
    for (int i=0;i<4;++i) t[ty+8*i][tx] = in[(size_t)(k0+ty+8*i)*N + n0+tx];
    __syncthreads();
    #pragma unroll
    for (int i=0;i<4;++i) out[(size_t)(n0+ty+8*i)*K + k0+tx] = __float2bfloat16(t[tx][ty+8*i]);
}

// ---------------- MFMA GEMM: C[M,N] = A[M,K] @ BT[N,K]^T (+bias) ----------------
// m97-style: 128x128 tile, BK=32, 256 threads (4 waves), wave = 64x64 = 4x4 MFMA 16x16x32.
// Staging via global_load_lds width 16. N % 128 == 0; M % 16 == 0 (row-clamped loads).
template<typename TC, bool BIAS>
__global__ __launch_bounds__(256) void k_gemm_mfma(
    const bf16* __restrict__ A, const bf16* __restrict__ BT,
    const float* __restrict__ bias, TC* __restrict__ Cout,
    int M, int N, int K)
{
    __shared__ __align__(16) bf16 sA[128*32];
    __shared__ __align__(16) bf16 sB[128*32];
    const int tid  = threadIdx.x;
    const int lane = tid & 63;
    const int w    = tid >> 6;
    const int wm   = w >> 1, wn = w & 1;
    const int m16  = lane & 15, q = lane >> 4;
    const int m0 = blockIdx.x * 128;
    const int n0 = blockIdx.y * 128;

    // staging chunks: chunk c in [0,512): row = c>>2 (tile row), kcol = (c&3)*8
    const int c0 = w*64 + lane;        // issue 0
    const int c1 = 256 + c0;           // issue 1
    const int rA0 = c0 >> 2, kA0 = (c0 & 3) * 8;
    const int rA1 = c1 >> 2, kA1 = (c1 & 3) * 8;
    const size_t gA0 = (size_t)min(m0 + rA0, M-1) * K + kA0;
    const size_t gA1 = (size_t)min(m0 + rA1, M-1) * K + kA1;
    const size_t gB0 = (size_t)(n0 + rA0) * K + kA0;
    const size_t gB1 = (size_t)(n0 + rA1) * K + kA1;

    f32x4 acc[4][4];
    #pragma unroll
    for (int i=0;i<4;++i)
        #pragma unroll
        for (int j=0;j<4;++j)
            #pragma unroll
            for (int r=0;r<4;++r) acc[i][j][r] = 0.f;

    for (int k0 = 0; k0 < K; k0 += 32){
        __syncthreads();   // previous iter's LDS reads complete
        gld_lds16(A  + gA0 + k0, sA + c0*8);
        gld_lds16(A  + gA1 + k0, sA + c1*8);
        gld_lds16(BT + gB0 + k0, sB + c0*8);
        gld_lds16(BT + gB1 + k0, sB + c1*8);
        __syncthreads();   // staging complete (compiler drains vmcnt)

        bf16x8 af[4], bfr[4];
        #pragma unroll
        for (int t=0;t<4;++t){
            af[t]  = *(const bf16x8*)(const void*)(sA + ((wm*64 + t*16 + m16)*32 + q*8));
            bfr[t] = *(const bf16x8*)(const void*)(sB + ((wn*64 + t*16 + m16)*32 + q*8));
        }
        #pragma unroll
        for (int i=0;i<4;++i)
            #pragma unroll
            for (int j=0;j<4;++j)
                acc[i][j] = __builtin_amdgcn_mfma_f32_16x16x32_bf16(af[i], bfr[j], acc[i][j], 0, 0, 0);
    }

    // C/D layout: col = lane&15, row = (lane>>4)*4 + reg  [m89-verified]
    #pragma unroll
    for (int i=0;i<4;++i){
        int row_base = m0 + wm*64 + i*16 + q*4;
        #pragma unroll
        for (int j=0;j<4;++j){
            int col = n0 + wn*64 + j*16 + m16;
            float bval = BIAS ? bias[col] : 0.f;
            #pragma unroll
            for (int r=0;r<4;++r){
                int row = row_base + r;
                if (row < M){
                    float v = acc[i][j][r] + bval;
                    if constexpr (std::is_same<TC, bf16>::value)
                        Cout[(size_t)row*N + col] = __float2bfloat16(v);
                    else
                        Cout[(size_t)row*N + col] = v;
                }
            }
        }
    }
}

// ---------------- per-node attention logits: a_src/a_dst [NN,NH] ----------------
__global__ __launch_bounds__(512) void k_attn(const bf16* __restrict__ h,
    const float* __restrict__ att_src, const float* __restrict__ att_dst,
    float* __restrict__ a_src, float* __restrict__ a_dst)
{
    int n = blockIdx.x;
    int w = threadIdx.x >> 6;    // head (8 waves/block)
    int lane = threadIdx.x & 63;
    const bf16*  hp = h + (size_t)n*HC + w*OC;
    const float* as = att_src + w*OC;
    const float* ad = att_dst + w*OC;
    float sa = 0.f, sd = 0.f;
    for (int c=lane; c<OC; c+=64){
        float hv = b2f(hp[c]);
        sa += hv * as[c];
        sd += hv * ad[c];
    }
    #pragma unroll
    for (int off=32; off; off>>=1){
        sa += __shfl_down(sa, off);
        sd += __shfl_down(sd, off);
    }
    if (lane == 0){
        a_src[n*NH + w] = sa;
        a_dst[n*NH + w] = sd;
    }
}

// ---------------- CSR build ----------------
__global__ void k_count(const int* __restrict__ eidx, int* __restrict__ counts){
    int e = blockIdx.x*blockDim.x + threadIdx.x;
    if (e >= NE2) return;
    int dst = (e < NE) ? eidx[NE + e] : (e - NE);
    atomicAdd(&counts[dst], 1);
}

__global__ __launch_bounds__(256) void k_scan(const int* __restrict__ counts, int* __restrict__ offsets){
    __shared__ int part[256];
    int t = threadIdx.x;
    int base = t*32;
    int s = 0;
    for (int u=0;u<32;++u){ int i = base+u; if (i<NN) s += counts[i]; }
    part[t] = s;
    __syncthreads();
    for (int off=1; off<256; off<<=1){
        int v = (t>=off) ? part[t-off] : 0;
        __syncthreads();
        part[t] += v;
        __syncthreads();
    }
    int run = (t==0) ? 0 : part[t-1];
    for (int u=0;u<32;++u){
        int i = base+u;
        if (i<NN){ offsets[i] = run; run += counts[i]; }
    }
    if (t == 255) offsets[NN] = run;   // == NE2
}

__global__ void k_fill(const int* __restrict__ eidx, const int* __restrict__ offsets,
                       int* __restrict__ cursors, int* __restrict__ esrc){
    int e = blockIdx.x*blockDim.x + threadIdx.x;
    if (e >= NE2) return;
    int src, dst;
    if (e < NE){ src = eidx[e]; dst = eidx[NE+e]; } else { src = dst = e - NE; }
    int pos = atomicAdd(&cursors[dst], 1);
    esrc[offsets[dst] + pos] = src;
}

// ---------------- per (node,head): segment max + 1/(sum exp) ----------------
__global__ void k_maxsum(const int* __restrict__ offsets, const int* __restrict__ esrc,
    const float* __restrict__ a_src, const float* __restrict__ a_dst,
    float* __restrict__ nmax, float* __restrict__ ninv)
{
    int t = blockIdx.x*blockDim.x + threadIdx.x;
    if (t >= NN*NH) return;
    int i = t >> 3, hh = t & 7;
    float ad = a_dst[t];
    int s0 = offsets[i], s1 = offsets[i+1];
    float m = -1e30f;
    for (int s=s0; s<s1; ++s){
        float l = a_src[esrc[s]*NH + hh] + ad;
        l = l > 0.f ? l : NEG_SLOPE*l;
        m = fmaxf(m, l);
    }
    float sum = 0.f;
    for (int s=s0; s<s1; ++s){
        float l = a_src[esrc[s]*NH + hh] + ad;
        l = l > 0.f ? l : NEG_SLOPE*l;
        sum += expf(l - m);
    }
    nmax[t] = m;
    ninv[t] = 1.f / (sum + 1e-16f);
}

// ---------------- per node: weighted aggregation of h -> agg ----------------
__global__ __launch_bounds__(256) void k_agg(const int* __restrict__ offsets,
    const int* __restrict__ esrc, const float* __restrict__ a_src,
    const float* __restrict__ a_dst, const float* __restrict__ nmax,
    const float* __restrict__ ninv, const bf16* __restrict__ h,
    bf16* __restrict__ agg)
{
    __shared__ float adst_s[NH], m_s[NH], inv_s[NH];
    __shared__ int   src_s[32];
    __shared__ float w_s[32][NH];
    int i = blockIdx.x;
    int tid = threadIdx.x;
    if (tid < NH){
        adst_s[tid] = a_dst[i*NH+tid];
        m_s[tid]    = nmax[i*NH+tid];
        inv_s[tid]  = ninv[i*NH+tid];
    }
    __syncthreads();
    float acc[16];
    #pragma unroll
    for (int j=0;j<16;++j) acc[j] = 0.f;
    int s0 = offsets[i], s1 = offsets[i+1];
    for (int c0=s0; c0<s1; c0+=32){
        int cnt = min(32, s1-c0);
        if (tid < cnt) src_s[tid] = esrc[c0+tid];
        __syncthreads();
        {
            int e = tid >> 3, hh = tid & 7;
            if (e < cnt){
                float l = a_src[src_s[e]*NH + hh] + adst_s[hh];
                l = l > 0.f ? l : NEG_SLOPE*l;
                w_s[e][hh] = expf(l - m_s[hh]) * inv_s[hh];
            }
        }
        __syncthreads();
        for (int e=0; e<cnt; ++e){
            const bf16* hp = h + (size_t)src_s[e]*HC + tid;
            #pragma unroll
            for (int j=0;j<16;++j){
                acc[j] += w_s[e][j>>1] * b2f(hp[j*256]);
            }
        }
        __syncthreads();
    }
    bf16* op = agg + (size_t)i*HC + tid;
    #pragma unroll
    for (int j=0;j<16;++j) op[j*256] = __float2bfloat16(acc[j]);
}

// ---------------- b_eff += b_gat @ W_lin (b_eff preloaded with b_lin) ----------------
__global__ __launch_bounds__(512) void k_beff(const float* __restrict__ b_gat,
    const float* __restrict__ W_lin, float* __restrict__ b_eff)
{
    int c  = threadIdx.x;
    int kb = blockIdx.x;         // 8 blocks x 512 k
    float acc = 0.f;
    for (int k = kb*512; k < (kb+1)*512; ++k)
        acc += b_gat[k] * W_lin[(size_t)k*NOUT + c];
    atomicAdd(&b_eff[c], acc);
}

extern "C" void kernel_launch(void* const* d_in, const int* in_sizes, int n_in,
                              void* d_out, int out_size, void* d_ws, size_t ws_size,
                              hipStream_t stream)
{
    const float* x       = (const float*)d_in[0];
    const int*   eidx    = (const int*)  d_in[1];
    const float* W_gat   = (const float*)d_in[2];
    const float* b_gat   = (const float*)d_in[3];
    const float* att_src = (const float*)d_in[4];
    const float* att_dst = (const float*)d_in[5];
    const float* W_lin   = (const float*)d_in[6];
    const float* b_lin   = (const float*)d_in[7];
    float* out = (float*)d_out;

    char* p = (char*)d_ws;
    auto alloc = [&](size_t bytes){ void* r = (void*)p; p += (bytes + 255) & ~(size_t)255; return r; };
    bf16*  h      = (bf16*) alloc((size_t)NN*HC*2);     // 65.5 MB
    bf16*  agg    = (bf16*) alloc((size_t)NN*HC*2);     // 65.5 MB
    float* a_src  = (float*)alloc((size_t)NN*NH*4);
    float* a_dst  = (float*)alloc((size_t)NN*NH*4);
    float* nmax   = (float*)alloc((size_t)NN*NH*4);
    float* ninv   = (float*)alloc((size_t)NN*NH*4);
    int*   offs   = (int*)  alloc((size_t)(NN+1)*4);
    int*   counts = (int*)  alloc((size_t)NN*4);
    int*   cursors= (int*)  alloc((size_t)NN*4);
    int*   esrc   = (int*)  alloc((size_t)NE2*4);
    float* b_eff  = (float*)alloc((size_t)NOUT*4);
    if ((size_t)(p - (char*)d_ws) > ws_size) return;  // ws too small: bail

    // aliased temporaries (no extra footprint):
    //  x_bf (2 MB) + Wg_t (1 MB) live in `agg` until k_agg writes it (GEMM1 is done by then)
    //  Wl_t (4 MB) lives in `h` after k_agg (h dead once agg is built)
    bf16* x_bf = agg;                                    // [NN][KIN]
    bf16* Wg_t = agg + (size_t)NN*KIN;                   // [HC][KIN]
    bf16* Wl_t = h;                                      // [NOUT][HC]

    k_init<<<32, 256, 0, stream>>>(counts, cursors, b_eff, b_lin);
    k_cvt <<<(NN*KIN/4+255)/256, 256, 0, stream>>>(x, x_bf, NN*KIN/4);
    k_tcvt<<<dim3(HC/32, KIN/32), 256, 0, stream>>>(W_gat, Wg_t, KIN, HC);
    k_gemm_mfma<bf16,false><<<dim3(63, HC/128), 256, 0, stream>>>(x_bf, Wg_t, nullptr, h, NN, HC, KIN);
    k_attn<<<NN, 512, 0, stream>>>(h, att_src, att_dst, a_src, a_dst);
    k_count<<<(NE2+255)/256, 256, 0, stream>>>(eidx, counts);
    k_scan<<<1, 256, 0, stream>>>(counts, offs);
    k_fill<<<(NE2+255)/256, 256, 0, stream>>>(eidx, offs, cursors, esrc);
    k_maxsum<<<(NN*NH+255)/256, 256, 0, stream>>>(offs, esrc, a_src, a_dst, nmax, ninv);
    k_agg<<<NN, 256, 0, stream>>>(offs, esrc, a_src, a_dst, nmax, ninv, h, agg);
    k_tcvt<<<dim3(NOUT/32, HC/32), 256, 0, stream>>>(W_lin, Wl_t, HC, NOUT);
    k_beff<<<8, 512, 0, stream>>>(b_gat, W_lin, b_eff);
    k_gemm_mfma<float,true><<<dim3(63, NOUT/128), 256, 0, stream>>>(agg, Wl_t, b_eff, out, NN, NOUT, HC);
}

// Round 4
// 348.528 us; speedup vs baseline: 2.5892x; 1.3826x over previous
//
#include <hip/hip_runtime.h>
#include <hip/hip_bf16.h>
#include <type_traits>

#define NN   8000
#define NE   64000
#define NE2  72000   // edges + self loops
#define NH   8
#define OC   512
#define HC   4096    // NH*OC
#define KIN  128
#define NOUT 512
#define NEG_SLOPE 0.2f

using bf16 = __hip_bfloat16;
typedef float  f32x4  __attribute__((ext_vector_type(4)));
typedef __bf16 bf16x8 __attribute__((ext_vector_type(8)));

static __device__ __forceinline__ float b2f(bf16 v){ return __bfloat162float(v); }

static __device__ __forceinline__ void gld_lds16(const bf16* g, bf16* l){
    __builtin_amdgcn_global_load_lds(
        (const __attribute__((address_space(1))) unsigned int*)g,
        (__attribute__((address_space(3))) unsigned int*)l, 16, 0, 0);
}

// ---------------- init: zero counters ----------------
__global__ void k_init(int* counts, int* cursors){
    int i = blockIdx.x*blockDim.x + threadIdx.x;
    if (i < NN){ counts[i] = 0; cursors[i] = 0; }
}

// ---------------- fp32 -> bf16 convert (n divisible by 4) ----------------
__global__ void k_cvt(const float* __restrict__ in, bf16* __restrict__ out, int n4){
    int i = blockIdx.x*blockDim.x + threadIdx.x;
    if (i >= n4) return;
    float4 v = reinterpret_cast<const float4*>(in)[i];
    ushort4 o;
    bf16 b0 = __float2bfloat16(v.x), b1 = __float2bfloat16(v.y);
    bf16 b2 = __float2bfloat16(v.z), b3 = __float2bfloat16(v.w);
    o.x = *(unsigned short*)&b0; o.y = *(unsigned short*)&b1;
    o.z = *(unsigned short*)&b2; o.w = *(unsigned short*)&b3;
    reinterpret_cast<ushort4*>(out)[i] = o;
}

// ---------------- transpose+convert: in[K][N] fp32 -> out[N][K] bf16 ----------------
__global__ __launch_bounds__(256) void k_tcvt(const float* __restrict__ in, bf16* __restrict__ out,
                                              int K, int N){
    __shared__ float t[32][33];
    int tx = threadIdx.x & 31, ty = threadIdx.x >> 5;   // 32 x 8
    int n0 = blockIdx.x*32, k0 = blockIdx.y*32;
    #pragma unroll
    for (int i=0;i<4;++i) t[ty+8*i][tx] = in[(size_t)(k0+ty+8*i)*N + n0+tx];
    __syncthreads();
    #pragma unroll
    for (int i=0;i<4;++i) out[(size_t)(n0+ty+8*i)*K + k0+tx] = __float2bfloat16(t[tx][ty+8*i]);
}

// ---------------- MFMA GEMM: C[M,N] = A[M,K] @ BT[N,K]^T (+bias) ----------------
template<typename TC, bool BIAS>
__global__ __launch_bounds__(256) void k_gemm_mfma(
    const bf16* __restrict__ A, const bf16* __restrict__ BT,
    const float* __restrict__ bias, TC* __restrict__ Cout,
    int M, int N, int K)
{
    __shared__ __align__(16) bf16 sA[128*32];
    __shared__ __align__(16) bf16 sB[128*32];
    const int tid  = threadIdx.x;
    const int lane = tid & 63;
    const int w    = tid >> 6;
    const int wm   = w >> 1, wn = w & 1;
    const int m16  = lane & 15, q = lane >> 4;
    const int m0 = blockIdx.x * 128;
    const int n0 = blockIdx.y * 128;

    const int c0 = w*64 + lane;
    const int c1 = 256 + c0;
    const int rA0 = c0 >> 2, kA0 = (c0 & 3) * 8;
    const int rA1 = c1 >> 2, kA1 = (c1 & 3) * 8;
    const size_t gA0 = (size_t)min(m0 + rA0, M-1) * K + kA0;
    const size_t gA1 = (size_t)min(m0 + rA1, M-1) * K + kA1;
    const size_t gB0 = (size_t)(n0 + rA0) * K + kA0;
    const size_t gB1 = (size_t)(n0 + rA1) * K + kA1;

    f32x4 acc[4][4];
    #pragma unroll
    for (int i=0;i<4;++i)
        #pragma unroll
        for (int j=0;j<4;++j)
            #pragma unroll
            for (int r=0;r<4;++r) acc[i][j][r] = 0.f;

    for (int k0 = 0; k0 < K; k0 += 32){
        __syncthreads();
        gld_lds16(A  + gA0 + k0, sA + c0*8);
        gld_lds16(A  + gA1 + k0, sA + c1*8);
        gld_lds16(BT + gB0 + k0, sB + c0*8);
        gld_lds16(BT + gB1 + k0, sB + c1*8);
        __syncthreads();

        bf16x8 af[4], bfr[4];
        #pragma unroll
        for (int t=0;t<4;++t){
            af[t]  = *(const bf16x8*)(const void*)(sA + ((wm*64 + t*16 + m16)*32 + q*8));
            bfr[t] = *(const bf16x8*)(const void*)(sB + ((wn*64 + t*16 + m16)*32 + q*8));
        }
        #pragma unroll
        for (int i=0;i<4;++i)
            #pragma unroll
            for (int j=0;j<4;++j)
                acc[i][j] = __builtin_amdgcn_mfma_f32_16x16x32_bf16(af[i], bfr[j], acc[i][j], 0, 0, 0);
    }

    // C/D layout: col = lane&15, row = (lane>>4)*4 + reg
    #pragma unroll
    for (int i=0;i<4;++i){
        int row_base = m0 + wm*64 + i*16 + q*4;
        #pragma unroll
        for (int j=0;j<4;++j){
            int col = n0 + wn*64 + j*16 + m16;
            float bval = BIAS ? bias[col] : 0.f;
            #pragma unroll
            for (int r=0;r<4;++r){
                int row = row_base + r;
                if (row < M){
                    float v = acc[i][j][r] + bval;
                    if constexpr (std::is_same<TC, bf16>::value)
                        Cout[(size_t)row*N + col] = __float2bfloat16(v);
                    else
                        Cout[(size_t)row*N + col] = v;
                }
            }
        }
    }
}

// ---------------- per-node attention logits: a_src/a_dst [NN,NH] ----------------
__global__ __launch_bounds__(512) void k_attn(const bf16* __restrict__ h,
    const float* __restrict__ att_src, const float* __restrict__ att_dst,
    float* __restrict__ a_src, float* __restrict__ a_dst)
{
    int n = blockIdx.x;
    int w = threadIdx.x >> 6;    // head
    int lane = threadIdx.x & 63;
    int c = lane * 8;            // OC = 512 = 64 lanes x 8
    bf16x8 hv = *(const bf16x8*)(const void*)(h + (size_t)n*HC + w*OC + c);
    const float4* as4 = (const float4*)(att_src + w*OC + c);
    const float4* ad4 = (const float4*)(att_dst + w*OC + c);
    float4 a0 = as4[0], a1 = as4[1];
    float4 d0 = ad4[0], d1 = ad4[1];
    float sa = (float)hv[0]*a0.x + (float)hv[1]*a0.y + (float)hv[2]*a0.z + (float)hv[3]*a0.w
             + (float)hv[4]*a1.x + (float)hv[5]*a1.y + (float)hv[6]*a1.z + (float)hv[7]*a1.w;
    float sd = (float)hv[0]*d0.x + (float)hv[1]*d0.y + (float)hv[2]*d0.z + (float)hv[3]*d0.w
             + (float)hv[4]*d1.x + (float)hv[5]*d1.y + (float)hv[6]*d1.z + (float)hv[7]*d1.w;
    #pragma unroll
    for (int off=32; off; off>>=1){
        sa += __shfl_down(sa, off);
        sd += __shfl_down(sd, off);
    }
    if (lane == 0){
        a_src[n*NH + w] = sa;
        a_dst[n*NH + w] = sd;
    }
}

// ---------------- CSR build ----------------
__global__ void k_count(const int* __restrict__ eidx, int* __restrict__ counts){
    int e = blockIdx.x*blockDim.x + threadIdx.x;
    if (e >= NE2) return;
    int dst = (e < NE) ? eidx[NE + e] : (e - NE);
    atomicAdd(&counts[dst], 1);
}

__global__ __launch_bounds__(256) void k_scan(const int* __restrict__ counts, int* __restrict__ offsets){
    __shared__ int part[256];
    int t = threadIdx.x;
    int base = t*32;
    int s = 0;
    for (int u=0;u<32;++u){ int i = base+u; if (i<NN) s += counts[i]; }
    part[t] = s;
    __syncthreads();
    for (int off=1; off<256; off<<=1){
        int v = (t>=off) ? part[t-off] : 0;
        __syncthreads();
        part[t] += v;
        __syncthreads();
    }
    int run = (t==0) ? 0 : part[t-1];
    for (int u=0;u<32;++u){
        int i = base+u;
        if (i<NN){ offsets[i] = run; run += counts[i]; }
    }
    if (t == 255) offsets[NN] = run;
}

__global__ void k_fill(const int* __restrict__ eidx, const int* __restrict__ offsets,
                       int* __restrict__ cursors, int* __restrict__ esrc){
    int e = blockIdx.x*blockDim.x + threadIdx.x;
    if (e >= NE2) return;
    int src, dst;
    if (e < NE){ src = eidx[e]; dst = eidx[NE+e]; } else { src = dst = e - NE; }
    int pos = atomicAdd(&cursors[dst], 1);
    esrc[offsets[dst] + pos] = src;
}

// ---------------- per (node,head): segment max + 1/(sum exp) ----------------
__global__ void k_maxsum(const int* __restrict__ offsets, const int* __restrict__ esrc,
    const float* __restrict__ a_src, const float* __restrict__ a_dst,
    float* __restrict__ nmax, float* __restrict__ ninv)
{
    int t = blockIdx.x*blockDim.x + threadIdx.x;
    if (t >= NN*NH) return;
    int i = t >> 3, hh = t & 7;
    float ad = a_dst[t];
    int s0 = offsets[i], s1 = offsets[i+1];
    float m = -1e30f;
    for (int s=s0; s<s1; ++s){
        float l = a_src[esrc[s]*NH + hh] + ad;
        l = l > 0.f ? l : NEG_SLOPE*l;
        m = fmaxf(m, l);
    }
    float sum = 0.f;
    for (int s=s0; s<s1; ++s){
        float l = a_src[esrc[s]*NH + hh] + ad;
        l = l > 0.f ? l : NEG_SLOPE*l;
        sum += expf(l - m);
    }
    nmax[t] = m;
    ninv[t] = 1.f / (sum + 1e-16f);
}

// ---------------- per node: weighted aggregation of h -> agg ----------------
// thread owns 16 CONTIGUOUS columns [tid*16, tid*16+16): two bf16x8 loads/edge.
__global__ __launch_bounds__(256) void k_agg(const int* __restrict__ offsets,
    const int* __restrict__ esrc, const float* __restrict__ a_src,
    const float* __restrict__ a_dst, const float* __restrict__ nmax,
    const float* __restrict__ ninv, const bf16* __restrict__ h,
    bf16* __restrict__ agg)
{
    __shared__ float adst_s[NH], m_s[NH], inv_s[NH];
    __shared__ int   src_s[32];
    __shared__ float w_s[32][NH];
    int i = blockIdx.x;
    int tid = threadIdx.x;
    int head = tid >> 5;                 // 32 threads per head (512 cols / 16)
    if (tid < NH){
        adst_s[tid] = a_dst[i*NH+tid];
        m_s[tid]    = nmax[i*NH+tid];
        inv_s[tid]  = ninv[i*NH+tid];
    }
    __syncthreads();
    float acc[16];
    #pragma unroll
    for (int j=0;j<16;++j) acc[j] = 0.f;
    int s0 = offsets[i], s1 = offsets[i+1];
    for (int c0=s0; c0<s1; c0+=32){
        int cnt = min(32, s1-c0);
        if (tid < cnt) src_s[tid] = esrc[c0+tid];
        __syncthreads();
        {
            int e = tid >> 3, hh = tid & 7;
            if (e < cnt){
                float l = a_src[src_s[e]*NH + hh] + adst_s[hh];
                l = l > 0.f ? l : NEG_SLOPE*l;
                w_s[e][hh] = expf(l - m_s[hh]) * inv_s[hh];
            }
        }
        __syncthreads();
        for (int e=0; e<cnt; ++e){
            const bf16* hp = h + (size_t)src_s[e]*HC + tid*16;
            bf16x8 v0 = *(const bf16x8*)(const void*)(hp);
            bf16x8 v1 = *(const bf16x8*)(const void*)(hp + 8);
            float wgt = w_s[e][head];
            #pragma unroll
            for (int j=0;j<8;++j){
                acc[j]   = fmaf(wgt, (float)v0[j], acc[j]);
                acc[8+j] = fmaf(wgt, (float)v1[j], acc[8+j]);
            }
        }
        __syncthreads();
    }
    bf16x8 o0, o1;
    #pragma unroll
    for (int j=0;j<8;++j){ o0[j] = (__bf16)acc[j]; o1[j] = (__bf16)acc[8+j]; }
    bf16* op = agg + (size_t)i*HC + tid*16;
    *(bf16x8*)(void*)(op)     = o0;
    *(bf16x8*)(void*)(op + 8) = o1;
}

// ---------------- b_eff[c] = b_lin[c] + b_gat @ Wl_t[c,:] (one wave per column) ----------------
__global__ __launch_bounds__(512) void k_beff(const float* __restrict__ b_gat,
    const bf16* __restrict__ Wl_t, const float* __restrict__ b_lin,
    float* __restrict__ b_eff)
{
    int c = blockIdx.x*8 + (threadIdx.x >> 6);
    int lane = threadIdx.x & 63;
    const bf16* wp = Wl_t + (size_t)c*HC;
    float s = 0.f;
    #pragma unroll
    for (int k0=0; k0<HC; k0+=512){
        int k = k0 + lane*8;
        bf16x8 wv = *(const bf16x8*)(const void*)(wp + k);
        float4 g0 = *(const float4*)(b_gat + k);
        float4 g1 = *(const float4*)(b_gat + k + 4);
        s += (float)wv[0]*g0.x + (float)wv[1]*g0.y + (float)wv[2]*g0.z + (float)wv[3]*g0.w
           + (float)wv[4]*g1.x + (float)wv[5]*g1.y + (float)wv[6]*g1.z + (float)wv[7]*g1.w;
    }
    #pragma unroll
    for (int off=32; off; off>>=1) s += __shfl_down(s, off);
    if (lane == 0) b_eff[c] = b_lin[c] + s;
}

extern "C" void kernel_launch(void* const* d_in, const int* in_sizes, int n_in,
                              void* d_out, int out_size, void* d_ws, size_t ws_size,
                              hipStream_t stream)
{
    const float* x       = (const float*)d_in[0];
    const int*   eidx    = (const int*)  d_in[1];
    const float* W_gat   = (const float*)d_in[2];
    const float* b_gat   = (const float*)d_in[3];
    const float* att_src = (const float*)d_in[4];
    const float* att_dst = (const float*)d_in[5];
    const float* W_lin   = (const float*)d_in[6];
    const float* b_lin   = (const float*)d_in[7];
    float* out = (float*)d_out;

    char* p = (char*)d_ws;
    auto alloc = [&](size_t bytes){ void* r = (void*)p; p += (bytes + 255) & ~(size_t)255; return r; };
    bf16*  h      = (bf16*) alloc((size_t)NN*HC*2);     // 65.5 MB
    bf16*  agg    = (bf16*) alloc((size_t)NN*HC*2);     // 65.5 MB
    float* a_src  = (float*)alloc((size_t)NN*NH*4);
    float* a_dst  = (float*)alloc((size_t)NN*NH*4);
    float* nmax   = (float*)alloc((size_t)NN*NH*4);
    float* ninv   = (float*)alloc((size_t)NN*NH*4);
    int*   offs   = (int*)  alloc((size_t)(NN+1)*4);
    int*   counts = (int*)  alloc((size_t)NN*4);
    int*   cursors= (int*)  alloc((size_t)NN*4);
    int*   esrc   = (int*)  alloc((size_t)NE2*4);
    float* b_eff  = (float*)alloc((size_t)NOUT*4);
    if ((size_t)(p - (char*)d_ws) > ws_size) return;

    // aliased temporaries:
    //  x_bf + Wg_t live in `agg` until k_agg writes it (GEMM1 done by then)
    //  Wl_t lives in `h` after k_agg (h dead once agg built)
    bf16* x_bf = agg;                                    // [NN][KIN]
    bf16* Wg_t = agg + (size_t)NN*KIN;                   // [HC][KIN]
    bf16* Wl_t = h;                                      // [NOUT][HC]

    k_init<<<32, 256, 0, stream>>>(counts, cursors);
    k_cvt <<<(NN*KIN/4+255)/256, 256, 0, stream>>>(x, x_bf, NN*KIN/4);
    k_tcvt<<<dim3(HC/32, KIN/32), 256, 0, stream>>>(W_gat, Wg_t, KIN, HC);
    k_gemm_mfma<bf16,false><<<dim3(63, HC/128), 256, 0, stream>>>(x_bf, Wg_t, nullptr, h, NN, HC, KIN);
    k_attn<<<NN, 512, 0, stream>>>(h, att_src, att_dst, a_src, a_dst);
    k_count<<<(NE2+255)/256, 256, 0, stream>>>(eidx, counts);
    k_scan<<<1, 256, 0, stream>>>(counts, offs);
    k_fill<<<(NE2+255)/256, 256, 0, stream>>>(eidx, offs, cursors, esrc);
    k_maxsum<<<(NN*NH+255)/256, 256, 0, stream>>>(offs, esrc, a_src, a_dst, nmax, ninv);
    k_agg<<<NN, 256, 0, stream>>>(offs, esrc, a_src, a_dst, nmax, ninv, h, agg);
    k_tcvt<<<dim3(NOUT/32, HC/32), 256, 0, stream>>>(W_lin, Wl_t, HC, NOUT);
    k_beff<<<NOUT/8, 512, 0, stream>>>(b_gat, Wl_t, b_lin, b_eff);
    k_gemm_mfma<float,true><<<dim3(63, NOUT/128), 256, 0, stream>>>(agg, Wl_t, b_eff, out, NN, NOUT, HC);
}

// Round 5
// 325.895 us; speedup vs baseline: 2.7690x; 1.0695x over previous
//
#include <hip/hip_runtime.h>
#include <hip/hip_bf16.h>
#include <type_traits>

#define NN   8000
#define NE   64000
#define NE2  72000   // edges + self loops
#define NH   8
#define OC   512
#define HC   4096    // NH*OC
#define KIN  128
#define NOUT 512
#define NEG_SLOPE 0.2f
#define SPLITK 4

using bf16 = __hip_bfloat16;
typedef float  f32x4  __attribute__((ext_vector_type(4)));
typedef __bf16 bf16x8 __attribute__((ext_vector_type(8)));

static __device__ __forceinline__ float b2f(bf16 v){ return __bfloat162float(v); }

static __device__ __forceinline__ void gld_lds16(const bf16* g, bf16* l){
    __builtin_amdgcn_global_load_lds(
        (const __attribute__((address_space(1))) unsigned int*)g,
        (__attribute__((address_space(3))) unsigned int*)l, 16, 0, 0);
}

// ---------------- init: zero counters ----------------
__global__ void k_init(int* counts, int* cursors){
    int i = blockIdx.x*blockDim.x + threadIdx.x;
    if (i < NN){ counts[i] = 0; cursors[i] = 0; }
}

// ---------------- fp32 -> bf16 convert ----------------
__global__ void k_cvt(const float* __restrict__ in, bf16* __restrict__ out, int n4){
    int i = blockIdx.x*blockDim.x + threadIdx.x;
    if (i >= n4) return;
    float4 v = reinterpret_cast<const float4*>(in)[i];
    ushort4 o;
    bf16 b0 = __float2bfloat16(v.x), b1 = __float2bfloat16(v.y);
    bf16 b2 = __float2bfloat16(v.z), b3 = __float2bfloat16(v.w);
    o.x = *(unsigned short*)&b0; o.y = *(unsigned short*)&b1;
    o.z = *(unsigned short*)&b2; o.w = *(unsigned short*)&b3;
    reinterpret_cast<ushort4*>(out)[i] = o;
}

// ---------------- transpose+convert: in[K][N] fp32 -> out[N][K] bf16 ----------------
__global__ __launch_bounds__(256) void k_tcvt(const float* __restrict__ in, bf16* __restrict__ out,
                                              int K, int N){
    __shared__ float t[32][33];
    int tx = threadIdx.x & 31, ty = threadIdx.x >> 5;
    int n0 = blockIdx.x*32, k0 = blockIdx.y*32;
    #pragma unroll
    for (int i=0;i<4;++i) t[ty+8*i][tx] = in[(size_t)(k0+ty+8*i)*N + n0+tx];
    __syncthreads();
    #pragma unroll
    for (int i=0;i<4;++i) out[(size_t)(n0+ty+8*i)*K + k0+tx] = __float2bfloat16(t[tx][ty+8*i]);
}

// ---------------- MFMA GEMM (single-buffer): C = A @ BT^T, used for GEMM1 ----------------
template<typename TC, bool BIAS>
__global__ __launch_bounds__(256) void k_gemm_mfma(
    const bf16* __restrict__ A, const bf16* __restrict__ BT,
    const float* __restrict__ bias, TC* __restrict__ Cout,
    int M, int N, int K)
{
    __shared__ __align__(16) bf16 sA[128*32];
    __shared__ __align__(16) bf16 sB[128*32];
    const int tid  = threadIdx.x;
    const int lane = tid & 63;
    const int w    = tid >> 6;
    const int wm   = w >> 1, wn = w & 1;
    const int m16  = lane & 15, q = lane >> 4;
    const int m0 = blockIdx.x * 128;
    const int n0 = blockIdx.y * 128;

    const int c0 = w*64 + lane;
    const int c1 = 256 + c0;
    const int rA0 = c0 >> 2, kA0 = (c0 & 3) * 8;
    const int rA1 = c1 >> 2, kA1 = (c1 & 3) * 8;
    const size_t gA0 = (size_t)min(m0 + rA0, M-1) * K + kA0;
    const size_t gA1 = (size_t)min(m0 + rA1, M-1) * K + kA1;
    const size_t gB0 = (size_t)(n0 + rA0) * K + kA0;
    const size_t gB1 = (size_t)(n0 + rA1) * K + kA1;

    f32x4 acc[4][4];
    #pragma unroll
    for (int i=0;i<4;++i)
        #pragma unroll
        for (int j=0;j<4;++j)
            #pragma unroll
            for (int r=0;r<4;++r) acc[i][j][r] = 0.f;

    for (int k0 = 0; k0 < K; k0 += 32){
        __syncthreads();
        gld_lds16(A  + gA0 + k0, sA + c0*8);
        gld_lds16(A  + gA1 + k0, sA + c1*8);
        gld_lds16(BT + gB0 + k0, sB + c0*8);
        gld_lds16(BT + gB1 + k0, sB + c1*8);
        __syncthreads();

        bf16x8 af[4], bfr[4];
        #pragma unroll
        for (int t=0;t<4;++t){
            af[t]  = *(const bf16x8*)(const void*)(sA + ((wm*64 + t*16 + m16)*32 + q*8));
            bfr[t] = *(const bf16x8*)(const void*)(sB + ((wn*64 + t*16 + m16)*32 + q*8));
        }
        #pragma unroll
        for (int i=0;i<4;++i)
            #pragma unroll
            for (int j=0;j<4;++j)
                acc[i][j] = __builtin_amdgcn_mfma_f32_16x16x32_bf16(af[i], bfr[j], acc[i][j], 0, 0, 0);
    }

    #pragma unroll
    for (int i=0;i<4;++i){
        int row_base = m0 + wm*64 + i*16 + q*4;
        #pragma unroll
        for (int j=0;j<4;++j){
            int col = n0 + wn*64 + j*16 + m16;
            float bval = BIAS ? bias[col] : 0.f;
            #pragma unroll
            for (int r=0;r<4;++r){
                int row = row_base + r;
                if (row < M){
                    float v = acc[i][j][r] + bval;
                    if constexpr (std::is_same<TC, bf16>::value)
                        Cout[(size_t)row*N + col] = __float2bfloat16(v);
                    else
                        Cout[(size_t)row*N + col] = v;
                }
            }
        }
    }
}

// ---------------- split-K MFMA GEMM w/ LDS double-buffer: partials (bf16) ----------------
// grid (M/128, N/128, SPLITK); part layout [kz][M][N]
__global__ __launch_bounds__(256) void k_gemm_sk(
    const bf16* __restrict__ A, const bf16* __restrict__ BT,
    bf16* __restrict__ part, int M, int N, int K)
{
    __shared__ __align__(16) bf16 sA[2][128*32];
    __shared__ __align__(16) bf16 sB[2][128*32];
    const int tid  = threadIdx.x;
    const int lane = tid & 63;
    const int w    = tid >> 6;
    const int wm   = w >> 1, wn = w & 1;
    const int m16  = lane & 15, q = lane >> 4;
    const int m0 = blockIdx.x * 128;
    const int n0 = blockIdx.y * 128;
    const int kz = blockIdx.z;
    const int Ks = K / SPLITK;
    const int kbase = kz * Ks;

    const int c0 = w*64 + lane;
    const int c1 = 256 + c0;
    const int rA0 = c0 >> 2, kA0 = (c0 & 3) * 8;
    const int rA1 = c1 >> 2, kA1 = (c1 & 3) * 8;
    const size_t gA0 = (size_t)min(m0 + rA0, M-1) * K + kA0 + kbase;
    const size_t gA1 = (size_t)min(m0 + rA1, M-1) * K + kA1 + kbase;
    const size_t gB0 = (size_t)(n0 + rA0) * K + kA0 + kbase;
    const size_t gB1 = (size_t)(n0 + rA1) * K + kA1 + kbase;

    f32x4 acc[4][4];
    #pragma unroll
    for (int i=0;i<4;++i)
        #pragma unroll
        for (int j=0;j<4;++j)
            #pragma unroll
            for (int r=0;r<4;++r) acc[i][j][r] = 0.f;

    // prologue: stage iter 0 into buf 0
    gld_lds16(A  + gA0, sA[0] + c0*8);
    gld_lds16(A  + gA1, sA[0] + c1*8);
    gld_lds16(BT + gB0, sB[0] + c0*8);
    gld_lds16(BT + gB1, sB[0] + c1*8);
    __syncthreads();

    const int nIter = Ks / 32;
    for (int it = 0; it < nIter; ++it){
        const int cur = it & 1, nxt = cur ^ 1;
        // read fragments from cur FIRST (no vmcnt dependence on the new stage)
        bf16x8 af[4], bfr[4];
        #pragma unroll
        for (int t=0;t<4;++t){
            af[t]  = *(const bf16x8*)(const void*)(sA[cur] + ((wm*64 + t*16 + m16)*32 + q*8));
            bfr[t] = *(const bf16x8*)(const void*)(sB[cur] + ((wn*64 + t*16 + m16)*32 + q*8));
        }
        // issue next stage into nxt; overlaps with MFMA below
        if (it + 1 < nIter){
            int ko = (it+1) * 32;
            gld_lds16(A  + gA0 + ko, sA[nxt] + c0*8);
            gld_lds16(A  + gA1 + ko, sA[nxt] + c1*8);
            gld_lds16(BT + gB0 + ko, sB[nxt] + c0*8);
            gld_lds16(BT + gB1 + ko, sB[nxt] + c1*8);
        }
        #pragma unroll
        for (int i=0;i<4;++i)
            #pragma unroll
            for (int j=0;j<4;++j)
                acc[i][j] = __builtin_amdgcn_mfma_f32_16x16x32_bf16(af[i], bfr[j], acc[i][j], 0, 0, 0);
        __syncthreads();   // drains vmcnt -> nxt ready; cur safe to overwrite next iter
    }

    bf16* pout = part + (size_t)kz * M * N;
    #pragma unroll
    for (int i=0;i<4;++i){
        int row_base = m0 + wm*64 + i*16 + q*4;
        #pragma unroll
        for (int j=0;j<4;++j){
            int col = n0 + wn*64 + j*16 + m16;
            #pragma unroll
            for (int r=0;r<4;++r){
                int row = row_base + r;
                if (row < M)
                    pout[(size_t)row*N + col] = __float2bfloat16(acc[i][j][r]);
            }
        }
    }
}

// ---------------- reduce split-K partials + bias -> out (fp32) ----------------
__global__ __launch_bounds__(256) void k_reduce(const bf16* __restrict__ part,
    const float* __restrict__ b_eff, float* __restrict__ out)
{
    int t = blockIdx.x*blockDim.x + threadIdx.x;   // 8 elems/thread
    if (t >= NN*NOUT/8) return;
    int base = t*8;
    int col = base & (NOUT-1);
    float s[8];
    float4 be0 = *(const float4*)(b_eff + col);
    float4 be1 = *(const float4*)(b_eff + col + 4);
    s[0]=be0.x; s[1]=be0.y; s[2]=be0.z; s[3]=be0.w;
    s[4]=be1.x; s[5]=be1.y; s[6]=be1.z; s[7]=be1.w;
    #pragma unroll
    for (int kz=0; kz<SPLITK; ++kz){
        bf16x8 v = *(const bf16x8*)(const void*)(part + (size_t)kz*NN*NOUT + base);
        #pragma unroll
        for (int j=0;j<8;++j) s[j] += (float)v[j];
    }
    float4 o0, o1;
    o0.x=s[0]; o0.y=s[1]; o0.z=s[2]; o0.w=s[3];
    o1.x=s[4]; o1.y=s[5]; o1.z=s[6]; o1.w=s[7];
    *(float4*)(out + base)     = o0;
    *(float4*)(out + base + 4) = o1;
}

// ---------------- per-node attention logits ----------------
__global__ __launch_bounds__(512) void k_attn(const bf16* __restrict__ h,
    const float* __restrict__ att_src, const float* __restrict__ att_dst,
    float* __restrict__ a_src, float* __restrict__ a_dst)
{
    int n = blockIdx.x;
    int w = threadIdx.x >> 6;
    int lane = threadIdx.x & 63;
    int c = lane * 8;
    bf16x8 hv = *(const bf16x8*)(const void*)(h + (size_t)n*HC + w*OC + c);
    const float4* as4 = (const float4*)(att_src + w*OC + c);
    const float4* ad4 = (const float4*)(att_dst + w*OC + c);
    float4 a0 = as4[0], a1 = as4[1];
    float4 d0 = ad4[0], d1 = ad4[1];
    float sa = (float)hv[0]*a0.x + (float)hv[1]*a0.y + (float)hv[2]*a0.z + (float)hv[3]*a0.w
             + (float)hv[4]*a1.x + (float)hv[5]*a1.y + (float)hv[6]*a1.z + (float)hv[7]*a1.w;
    float sd = (float)hv[0]*d0.x + (float)hv[1]*d0.y + (float)hv[2]*d0.z + (float)hv[3]*d0.w
             + (float)hv[4]*d1.x + (float)hv[5]*d1.y + (float)hv[6]*d1.z + (float)hv[7]*d1.w;
    #pragma unroll
    for (int off=32; off; off>>=1){
        sa += __shfl_down(sa, off);
        sd += __shfl_down(sd, off);
    }
    if (lane == 0){
        a_src[n*NH + w] = sa;
        a_dst[n*NH + w] = sd;
    }
}

// ---------------- CSR build ----------------
__global__ void k_count(const int* __restrict__ eidx, int* __restrict__ counts){
    int e = blockIdx.x*blockDim.x + threadIdx.x;
    if (e >= NE2) return;
    int dst = (e < NE) ? eidx[NE + e] : (e - NE);
    atomicAdd(&counts[dst], 1);
}

__global__ __launch_bounds__(256) void k_scan(const int* __restrict__ counts, int* __restrict__ offsets){
    __shared__ int part[256];
    int t = threadIdx.x;
    int base = t*32;
    int s = 0;
    for (int u=0;u<32;++u){ int i = base+u; if (i<NN) s += counts[i]; }
    part[t] = s;
    __syncthreads();
    for (int off=1; off<256; off<<=1){
        int v = (t>=off) ? part[t-off] : 0;
        __syncthreads();
        part[t] += v;
        __syncthreads();
    }
    int run = (t==0) ? 0 : part[t-1];
    for (int u=0;u<32;++u){
        int i = base+u;
        if (i<NN){ offsets[i] = run; run += counts[i]; }
    }
    if (t == 255) offsets[NN] = run;
}

__global__ void k_fill(const int* __restrict__ eidx, const int* __restrict__ offsets,
                       int* __restrict__ cursors, int* __restrict__ esrc){
    int e = blockIdx.x*blockDim.x + threadIdx.x;
    if (e >= NE2) return;
    int src, dst;
    if (e < NE){ src = eidx[e]; dst = eidx[NE+e]; } else { src = dst = e - NE; }
    int pos = atomicAdd(&cursors[dst], 1);
    esrc[offsets[dst] + pos] = src;
}

// ---------------- per (node,head): segment max + 1/(sum exp) ----------------
__global__ void k_maxsum(const int* __restrict__ offsets, const int* __restrict__ esrc,
    const float* __restrict__ a_src, const float* __restrict__ a_dst,
    float* __restrict__ nmax, float* __restrict__ ninv)
{
    int t = blockIdx.x*blockDim.x + threadIdx.x;
    if (t >= NN*NH) return;
    int i = t >> 3, hh = t & 7;
    float ad = a_dst[t];
    int s0 = offsets[i], s1 = offsets[i+1];
    float m = -1e30f;
    for (int s=s0; s<s1; ++s){
        float l = a_src[esrc[s]*NH + hh] + ad;
        l = l > 0.f ? l : NEG_SLOPE*l;
        m = fmaxf(m, l);
    }
    float sum = 0.f;
    for (int s=s0; s<s1; ++s){
        float l = a_src[esrc[s]*NH + hh] + ad;
        l = l > 0.f ? l : NEG_SLOPE*l;
        sum += expf(l - m);
    }
    nmax[t] = m;
    ninv[t] = 1.f / (sum + 1e-16f);
}

// ---------------- per node: weighted aggregation of h -> agg ----------------
__global__ __launch_bounds__(256) void k_agg(const int* __restrict__ offsets,
    const int* __restrict__ esrc, const float* __restrict__ a_src,
    const float* __restrict__ a_dst, const float* __restrict__ nmax,
    const float* __restrict__ ninv, const bf16* __restrict__ h,
    bf16* __restrict__ agg)
{
    __shared__ float adst_s[NH], m_s[NH], inv_s[NH];
    __shared__ int   src_s[32];
    __shared__ float w_s[32][NH];
    int i = blockIdx.x;
    int tid = threadIdx.x;
    int head = tid >> 5;
    if (tid < NH){
        adst_s[tid] = a_dst[i*NH+tid];
        m_s[tid]    = nmax[i*NH+tid];
        inv_s[tid]  = ninv[i*NH+tid];
    }
    __syncthreads();
    float acc[16];
    #pragma unroll
    for (int j=0;j<16;++j) acc[j] = 0.f;
    int s0 = offsets[i], s1 = offsets[i+1];
    for (int c0=s0; c0<s1; c0+=32){
        int cnt = min(32, s1-c0);
        if (tid < cnt) src_s[tid] = esrc[c0+tid];
        __syncthreads();
        {
            int e = tid >> 3, hh = tid & 7;
            if (e < cnt){
                float l = a_src[src_s[e]*NH + hh] + adst_s[hh];
                l = l > 0.f ? l : NEG_SLOPE*l;
                w_s[e][hh] = expf(l - m_s[hh]) * inv_s[hh];
            }
        }
        __syncthreads();
        for (int e=0; e<cnt; ++e){
            const bf16* hp = h + (size_t)src_s[e]*HC + tid*16;
            bf16x8 v0 = *(const bf16x8*)(const void*)(hp);
            bf16x8 v1 = *(const bf16x8*)(const void*)(hp + 8);
            float wgt = w_s[e][head];
            #pragma unroll
            for (int j=0;j<8;++j){
                acc[j]   = fmaf(wgt, (float)v0[j], acc[j]);
                acc[8+j] = fmaf(wgt, (float)v1[j], acc[8+j]);
            }
        }
        __syncthreads();
    }
    bf16x8 o0, o1;
    #pragma unroll
    for (int j=0;j<8;++j){ o0[j] = (__bf16)acc[j]; o1[j] = (__bf16)acc[8+j]; }
    bf16* op = agg + (size_t)i*HC + tid*16;
    *(bf16x8*)(void*)(op)     = o0;
    *(bf16x8*)(void*)(op + 8) = o1;
}

// ---------------- b_eff[c] = b_lin[c] + b_gat @ Wl_t[c,:] ----------------
__global__ __launch_bounds__(512) void k_beff(const float* __restrict__ b_gat,
    const bf16* __restrict__ Wl_t, const float* __restrict__ b_lin,
    float* __restrict__ b_eff)
{
    int c = blockIdx.x*8 + (threadIdx.x >> 6);
    int lane = threadIdx.x & 63;
    const bf16* wp = Wl_t + (size_t)c*HC;
    float s = 0.f;
    #pragma unroll
    for (int k0=0; k0<HC; k0+=512){
        int k = k0 + lane*8;
        bf16x8 wv = *(const bf16x8*)(const void*)(wp + k);
        float4 g0 = *(const float4*)(b_gat + k);
        float4 g1 = *(const float4*)(b_gat + k + 4);
        s += (float)wv[0]*g0.x + (float)wv[1]*g0.y + (float)wv[2]*g0.z + (float)wv[3]*g0.w
           + (float)wv[4]*g1.x + (float)wv[5]*g1.y + (float)wv[6]*g1.z + (float)wv[7]*g1.w;
    }
    #pragma unroll
    for (int off=32; off; off>>=1) s += __shfl_down(s, off);
    if (lane == 0) b_eff[c] = b_lin[c] + s;
}

extern "C" void kernel_launch(void* const* d_in, const int* in_sizes, int n_in,
                              void* d_out, int out_size, void* d_ws, size_t ws_size,
                              hipStream_t stream)
{
    const float* x       = (const float*)d_in[0];
    const int*   eidx    = (const int*)  d_in[1];
    const float* W_gat   = (const float*)d_in[2];
    const float* b_gat   = (const float*)d_in[3];
    const float* att_src = (const float*)d_in[4];
    const float* att_dst = (const float*)d_in[5];
    const float* W_lin   = (const float*)d_in[6];
    const float* b_lin   = (const float*)d_in[7];
    float* out = (float*)d_out;

    char* p = (char*)d_ws;
    auto alloc = [&](size_t bytes){ void* r = (void*)p; p += (bytes + 255) & ~(size_t)255; return r; };
    bf16*  h      = (bf16*) alloc((size_t)NN*HC*2);     // 65.5 MB
    bf16*  agg    = (bf16*) alloc((size_t)NN*HC*2);     // 65.5 MB
    float* a_src  = (float*)alloc((size_t)NN*NH*4);
    float* a_dst  = (float*)alloc((size_t)NN*NH*4);
    float* nmax   = (float*)alloc((size_t)NN*NH*4);
    float* ninv   = (float*)alloc((size_t)NN*NH*4);
    int*   offs   = (int*)  alloc((size_t)(NN+1)*4);
    int*   counts = (int*)  alloc((size_t)NN*4);
    int*   cursors= (int*)  alloc((size_t)NN*4);
    int*   esrc   = (int*)  alloc((size_t)NE2*4);
    float* b_eff  = (float*)alloc((size_t)NOUT*4);
    if ((size_t)(p - (char*)d_ws) > ws_size) return;

    // aliased temporaries:
    //  x_bf + Wg_t live in `agg` until k_agg writes it (GEMM1 done by then)
    //  After k_agg, h is dead: Wl_t takes h[0:4MB]; split-K partials take the next 32.8MB
    bf16* x_bf  = agg;                                      // [NN][KIN]      2 MB
    bf16* Wg_t  = agg + (size_t)NN*KIN;                     // [HC][KIN]      1 MB
    bf16* Wl_t  = h;                                        // [NOUT][HC]     4 MB
    bf16* partk = h + (size_t)NOUT*HC;                      // [SPLITK][NN][NOUT] 32.8 MB (fits in h's 65.5)

    k_init<<<32, 256, 0, stream>>>(counts, cursors);
    k_cvt <<<(NN*KIN/4+255)/256, 256, 0, stream>>>(x, x_bf, NN*KIN/4);
    k_tcvt<<<dim3(HC/32, KIN/32), 256, 0, stream>>>(W_gat, Wg_t, KIN, HC);
    k_gemm_mfma<bf16,false><<<dim3(63, HC/128), 256, 0, stream>>>(x_bf, Wg_t, nullptr, h, NN, HC, KIN);
    k_attn<<<NN, 512, 0, stream>>>(h, att_src, att_dst, a_src, a_dst);
    k_count<<<(NE2+255)/256, 256, 0, stream>>>(eidx, counts);
    k_scan<<<1, 256, 0, stream>>>(counts, offs);
    k_fill<<<(NE2+255)/256, 256, 0, stream>>>(eidx, offs, cursors, esrc);
    k_maxsum<<<(NN*NH+255)/256, 256, 0, stream>>>(offs, esrc, a_src, a_dst, nmax, ninv);
    k_agg<<<NN, 256, 0, stream>>>(offs, esrc, a_src, a_dst, nmax, ninv, h, agg);
    k_tcvt<<<dim3(NOUT/32, HC/32), 256, 0, stream>>>(W_lin, Wl_t, HC, NOUT);
    k_beff<<<NOUT/8, 512, 0, stream>>>(b_gat, Wl_t, b_lin, b_eff);
    k_gemm_sk<<<dim3(63, NOUT/128, SPLITK), 256, 0, stream>>>(agg, Wl_t, partk, NN, NOUT, HC);
    k_reduce<<<(NN*NOUT/8+255)/256, 256, 0, stream>>>(partk, b_eff, out);
}

// Round 7
// 184.401 us; speedup vs baseline: 4.8937x; 1.7673x over previous
//
#include <hip/hip_runtime.h>
#include <hip/hip_bf16.h>
#include <type_traits>

#define NN   8000
#define NE   64000
#define NE2  72000   // edges + self loops
#define NH   8
#define OC   512
#define HC   4096    // NH*OC
#define KIN  128
#define NOUT 512
#define YW   1024    // NH*KIN
#define NEG_SLOPE 0.2f

using bf16 = __hip_bfloat16;
typedef float  f32x4  __attribute__((ext_vector_type(4)));
typedef __bf16 bf16x8 __attribute__((ext_vector_type(8)));

static __device__ __forceinline__ void gld_lds16(const bf16* g, bf16* l){
    __builtin_amdgcn_global_load_lds(
        (const __attribute__((address_space(1))) unsigned int*)g,
        (__attribute__((address_space(3))) unsigned int*)l, 16, 0, 0);
}

// ---------------- init ----------------
__global__ void k_init(int* counts, int* cursors){
    int i = blockIdx.x*blockDim.x + threadIdx.x;
    if (i < NN){ counts[i] = 0; cursors[i] = 0; }
}

// ---------------- fp32 -> bf16 flat convert ----------------
__global__ void k_cvt(const float* __restrict__ in, bf16* __restrict__ out, int n4){
    int i = blockIdx.x*blockDim.x + threadIdx.x;
    if (i >= n4) return;
    float4 v = reinterpret_cast<const float4*>(in)[i];
    ushort4 o;
    bf16 b0 = __float2bfloat16(v.x), b1 = __float2bfloat16(v.y);
    bf16 b2 = __float2bfloat16(v.z), b3 = __float2bfloat16(v.w);
    o.x = *(unsigned short*)&b0; o.y = *(unsigned short*)&b1;
    o.z = *(unsigned short*)&b2; o.w = *(unsigned short*)&b3;
    reinterpret_cast<ushort4*>(out)[i] = o;
}

// ---------------- transpose+convert: in[K][N] fp32 -> out[N][K] bf16 ----------------
__global__ __launch_bounds__(256) void k_tcvt(const float* __restrict__ in, bf16* __restrict__ out,
                                              int K, int N){
    __shared__ float t[32][33];
    int tx = threadIdx.x & 31, ty = threadIdx.x >> 5;
    int n0 = blockIdx.x*32, k0 = blockIdx.y*32;
    #pragma unroll
    for (int i=0;i<4;++i) t[ty+8*i][tx] = in[(size_t)(k0+ty+8*i)*N + n0+tx];
    __syncthreads();
    #pragma unroll
    for (int i=0;i<4;++i) out[(size_t)(n0+ty+8*i)*K + k0+tx] = __float2bfloat16(t[tx][ty+8*i]);
}

// ---------------- generalized MFMA GEMM, LDS double-buffered ----------------
// C[row*ldc+col] = sum_k A[row*lda+k] * BT[col*ldb+k] (+ bias[col])
// grid (ceil(M/128), N/128, Z); per-z element offsets offAz/offBz/offCz.
// K % 32 == 0. Row loads clamped to M-1 (writes guarded).
template<typename TC, bool BIAS>
__global__ __launch_bounds__(256) void k_gemm_g(
    const bf16* __restrict__ A, const bf16* __restrict__ BT,
    const float* __restrict__ bias, TC* __restrict__ C,
    int M, int N, int K, int lda, int ldb, int ldc,
    int offAz, int offBz, int offCz)
{
    A  += (size_t)blockIdx.z * offAz;
    BT += (size_t)blockIdx.z * offBz;
    C  += (size_t)blockIdx.z * offCz;
    __shared__ __align__(16) bf16 sA[2][128*32];
    __shared__ __align__(16) bf16 sB[2][128*32];
    const int tid  = threadIdx.x;
    const int lane = tid & 63;
    const int w    = tid >> 6;
    const int wm   = w >> 1, wn = w & 1;
    const int m16  = lane & 15, q = lane >> 4;
    const int m0 = blockIdx.x * 128;
    const int n0 = blockIdx.y * 128;

    const int c0 = w*64 + lane;
    const int c1 = 256 + c0;
    const int rA0 = c0 >> 2, kA0 = (c0 & 3) * 8;
    const int rA1 = c1 >> 2, kA1 = (c1 & 3) * 8;
    const size_t gA0 = (size_t)min(m0 + rA0, M-1) * lda + kA0;
    const size_t gA1 = (size_t)min(m0 + rA1, M-1) * lda + kA1;
    const size_t gB0 = (size_t)(n0 + rA0) * ldb + kA0;
    const size_t gB1 = (size_t)(n0 + rA1) * ldb + kA1;

    f32x4 acc[4][4];
    #pragma unroll
    for (int i=0;i<4;++i)
        #pragma unroll
        for (int j=0;j<4;++j)
            #pragma unroll
            for (int r=0;r<4;++r) acc[i][j][r] = 0.f;

    gld_lds16(A  + gA0, sA[0] + c0*8);
    gld_lds16(A  + gA1, sA[0] + c1*8);
    gld_lds16(BT + gB0, sB[0] + c0*8);
    gld_lds16(BT + gB1, sB[0] + c1*8);
    __syncthreads();

    const int nIter = K / 32;
    for (int it = 0; it < nIter; ++it){
        const int cur = it & 1, nxt = cur ^ 1;
        bf16x8 af[4], bfr[4];
        #pragma unroll
        for (int t=0;t<4;++t){
            af[t]  = *(const bf16x8*)(const void*)(sA[cur] + ((wm*64 + t*16 + m16)*32 + q*8));
            bfr[t] = *(const bf16x8*)(const void*)(sB[cur] + ((wn*64 + t*16 + m16)*32 + q*8));
        }
        if (it + 1 < nIter){
            int ko = (it+1) * 32;
            gld_lds16(A  + gA0 + ko, sA[nxt] + c0*8);
            gld_lds16(A  + gA1 + ko, sA[nxt] + c1*8);
            gld_lds16(BT + gB0 + ko, sB[nxt] + c0*8);
            gld_lds16(BT + gB1 + ko, sB[nxt] + c1*8);
        }
        #pragma unroll
        for (int i=0;i<4;++i)
            #pragma unroll
            for (int j=0;j<4;++j)
                acc[i][j] = __builtin_amdgcn_mfma_f32_16x16x32_bf16(af[i], bfr[j], acc[i][j], 0, 0, 0);
        __syncthreads();
    }

    // C/D layout: col = lane&15, row = (lane>>4)*4 + reg
    #pragma unroll
    for (int i=0;i<4;++i){
        int row_base = m0 + wm*64 + i*16 + q*4;
        #pragma unroll
        for (int j=0;j<4;++j){
            int col = n0 + wn*64 + j*16 + m16;
            float bval = BIAS ? bias[col] : 0.f;
            #pragma unroll
            for (int r=0;r<4;++r){
                int row = row_base + r;
                if (row < M){
                    float v = acc[i][j][r] + bval;
                    if constexpr (std::is_same<TC, bf16>::value)
                        C[(size_t)row*ldc + col] = __float2bfloat16(v);
                    else
                        C[(size_t)row*ldc + col] = v;
                }
            }
        }
    }
}

// ---------------- v[k][o]: o<8 -> src head o, o>=8 -> dst head o-8 ----------------
__global__ __launch_bounds__(512) void k_vsrc(const float* __restrict__ W_gat,
    const float* __restrict__ att_src, const float* __restrict__ att_dst,
    float* __restrict__ v)
{
    int k = blockIdx.x;
    int hh = threadIdx.x >> 6;
    int lane = threadIdx.x & 63;
    const float* wp = W_gat + (size_t)k*HC + hh*OC;
    const float* as = att_src + hh*OC;
    const float* ad = att_dst + hh*OC;
    float ss = 0.f, sd = 0.f;
    #pragma unroll
    for (int c0=0; c0<OC; c0+=64){
        float wv = wp[c0+lane];
        ss += wv * as[c0+lane];
        sd += wv * ad[c0+lane];
    }
    #pragma unroll
    for (int off=32; off; off>>=1){
        ss += __shfl_down(ss, off);
        sd += __shfl_down(sd, off);
    }
    if (lane == 0){
        v[k*16 + hh]     = ss;
        v[k*16 + 8 + hh] = sd;
    }
}

// ---------------- a_src/a_dst [NN][NH] fp32 = x @ v ----------------
__global__ __launch_bounds__(256) void k_attn2(const float* __restrict__ x,
    const float* __restrict__ v, float* __restrict__ a_src, float* __restrict__ a_dst)
{
    int t = blockIdx.x*blockDim.x + threadIdx.x;   // over NN*16
    int node = t >> 4, o = t & 15;
    const float* xp = x + (size_t)node*KIN;
    float acc = 0.f;
    #pragma unroll
    for (int k=0; k<KIN; ++k)
        acc = fmaf(xp[k], v[k*16 + o], acc);
    if (o < 8) a_src[node*NH + o]     = acc;
    else       a_dst[node*NH + o - 8] = acc;
}

// ---------------- CSR build ----------------
__global__ void k_count(const int* __restrict__ eidx, int* __restrict__ counts){
    int e = blockIdx.x*blockDim.x + threadIdx.x;
    if (e >= NE2) return;
    int dst = (e < NE) ? eidx[NE + e] : (e - NE);
    atomicAdd(&counts[dst], 1);
}

__global__ __launch_bounds__(256) void k_scan(const int* __restrict__ counts, int* __restrict__ offsets){
    __shared__ int part[256];
    int t = threadIdx.x;
    int base = t*32;
    int s = 0;
    for (int u=0;u<32;++u){ int i = base+u; if (i<NN) s += counts[i]; }
    part[t] = s;
    __syncthreads();
    for (int off=1; off<256; off<<=1){
        int vv = (t>=off) ? part[t-off] : 0;
        __syncthreads();
        part[t] += vv;
        __syncthreads();
    }
    int run = (t==0) ? 0 : part[t-1];
    for (int u=0;u<32;++u){
        int i = base+u;
        if (i<NN){ offsets[i] = run; run += counts[i]; }
    }
    if (t == 255) offsets[NN] = run;
}

__global__ void k_fill(const int* __restrict__ eidx, const int* __restrict__ offsets,
                       int* __restrict__ cursors, int* __restrict__ esrc){
    int e = blockIdx.x*blockDim.x + threadIdx.x;
    if (e >= NE2) return;
    int src, dst;
    if (e < NE){ src = eidx[e]; dst = eidx[NE+e]; } else { src = dst = e - NE; }
    int pos = atomicAdd(&cursors[dst], 1);
    esrc[offsets[dst] + pos] = src;
}

// ---------------- per (node,head): segment max + 1/(sum exp) ----------------
__global__ void k_maxsum(const int* __restrict__ offsets, const int* __restrict__ esrc,
    const float* __restrict__ a_src, const float* __restrict__ a_dst,
    float* __restrict__ nmax, float* __restrict__ ninv)
{
    int t = blockIdx.x*blockDim.x + threadIdx.x;
    if (t >= NN*NH) return;
    int i = t >> 3, hh = t & 7;
    float ad = a_dst[t];
    int s0 = offsets[i], s1 = offsets[i+1];
    float m = -1e30f;
    for (int s=s0; s<s1; ++s){
        float l = a_src[esrc[s]*NH + hh] + ad;
        l = l > 0.f ? l : NEG_SLOPE*l;
        m = fmaxf(m, l);
    }
    float sum = 0.f;
    for (int s=s0; s<s1; ++s){
        float l = a_src[esrc[s]*NH + hh] + ad;
        l = l > 0.f ? l : NEG_SLOPE*l;
        sum += expf(l - m);
    }
    nmax[t] = m;
    ninv[t] = 1.f / (sum + 1e-16f);
}

// ---------------- Y[n][h*128+k] = sum_e alpha[e,h] * x[src_e][k]  (bf16 out) ----------------
// wave per node; lane owns x-cols {2*lane, 2*lane+1} for ALL 8 heads (16 fp32 acc).
__global__ __launch_bounds__(256) void k_aggx(const int* __restrict__ offs,
    const int* __restrict__ esrc, const float* __restrict__ a_src,
    const float* __restrict__ a_dst, const float* __restrict__ nmax,
    const float* __restrict__ ninv, const float* __restrict__ x,
    bf16* __restrict__ Y)
{
    int node = blockIdx.x*4 + (threadIdx.x >> 6);
    int lane = threadIdx.x & 63;
    float adl = 0.f, ml = 0.f, invl = 0.f;
    if (lane < 8){
        adl  = a_dst[node*NH + lane];
        ml   = nmax[node*NH + lane];
        invl = ninv[node*NH + lane];
    }
    float acc[16];
    #pragma unroll
    for (int j=0;j<16;++j) acc[j] = 0.f;
    int s0 = offs[node], s1 = offs[node+1];
    for (int s=s0; s<s1; ++s){
        int src = esrc[s];
        float wl = 0.f;
        if (lane < 8){
            float l = a_src[src*NH + lane] + adl;
            l = l > 0.f ? l : NEG_SLOPE*l;
            wl = __expf(l - ml) * invl;
        }
        float2 xv = *(const float2*)(x + (size_t)src*KIN + lane*2);
        #pragma unroll
        for (int h=0; h<8; ++h){
            float wh = __shfl(wl, h);
            acc[h*2]   = fmaf(wh, xv.x, acc[h*2]);
            acc[h*2+1] = fmaf(wh, xv.y, acc[h*2+1]);
        }
    }
    bf16* yp = Y + (size_t)node*YW + lane*2;
    #pragma unroll
    for (int h=0; h<8; ++h){
        bf16 b0 = __float2bfloat16(acc[h*2]);
        bf16 b1 = __float2bfloat16(acc[h*2+1]);
        ushort2 pk;
        pk.x = *(unsigned short*)&b0;
        pk.y = *(unsigned short*)&b1;
        *reinterpret_cast<ushort2*>(yp + h*KIN) = pk;
    }
}

// ---------------- b_eff[c] = b_lin[c] + b_gat @ Wl_t[c,:] (wave per column) ----------------
__global__ __launch_bounds__(512) void k_beff(const float* __restrict__ b_gat,
    const bf16* __restrict__ Wl_t, const float* __restrict__ b_lin,
    float* __restrict__ b_eff)
{
    int c = blockIdx.x*8 + (threadIdx.x >> 6);
    int lane = threadIdx.x & 63;
    const bf16* wp = Wl_t + (size_t)c*HC;
    float s = 0.f;
    #pragma unroll
    for (int k0=0; k0<HC; k0+=512){
        int k = k0 + lane*8;
        bf16x8 wv = *(const bf16x8*)(const void*)(wp + k);
        float4 g0 = *(const float4*)(b_gat + k);
        float4 g1 = *(const float4*)(b_gat + k + 4);
        s += (float)wv[0]*g0.x + (float)wv[1]*g0.y + (float)wv[2]*g0.z + (float)wv[3]*g0.w
           + (float)wv[4]*g1.x + (float)wv[5]*g1.y + (float)wv[6]*g1.z + (float)wv[7]*g1.w;
    }
    #pragma unroll
    for (int off=32; off; off>>=1) s += __shfl_down(s, off);
    if (lane == 0) b_eff[c] = b_lin[c] + s;
}

extern "C" void kernel_launch(void* const* d_in, const int* in_sizes, int n_in,
                              void* d_out, int out_size, void* d_ws, size_t ws_size,
                              hipStream_t stream)
{
    const float* x       = (const float*)d_in[0];
    const int*   eidx    = (const int*)  d_in[1];
    const float* W_gat   = (const float*)d_in[2];
    const float* b_gat   = (const float*)d_in[3];
    const float* att_src = (const float*)d_in[4];
    const float* att_dst = (const float*)d_in[5];
    const float* W_lin   = (const float*)d_in[6];
    const float* b_lin   = (const float*)d_in[7];
    float* out = (float*)d_out;

    char* p = (char*)d_ws;
    auto alloc = [&](size_t bytes){ void* r = (void*)p; p += (bytes + 255) & ~(size_t)255; return r; };
    bf16*  Wg_bf  = (bf16*) alloc((size_t)KIN*HC*2);      // 1 MB   [128][4096]
    bf16*  Wl_t   = (bf16*) alloc((size_t)NOUT*HC*2);     // 4 MB   [512][4096]
    bf16*  WcT    = (bf16*) alloc((size_t)NOUT*YW*2);     // 1 MB   [512][1024]  Wc^T
    bf16*  Ybuf   = (bf16*) alloc((size_t)NN*YW*2);       // 16.4 MB [8000][1024]
    float* v      = (float*)alloc((size_t)KIN*16*4);
    float* a_src  = (float*)alloc((size_t)NN*NH*4);
    float* a_dst  = (float*)alloc((size_t)NN*NH*4);
    float* nmax   = (float*)alloc((size_t)NN*NH*4);
    float* ninv   = (float*)alloc((size_t)NN*NH*4);
    int*   offs   = (int*)  alloc((size_t)(NN+1)*4);
    int*   counts = (int*)  alloc((size_t)NN*4);
    int*   cursors= (int*)  alloc((size_t)NN*4);
    int*   esrc   = (int*)  alloc((size_t)NE2*4);
    float* b_eff  = (float*)alloc((size_t)NOUT*4);
    if ((size_t)(p - (char*)d_ws) > ws_size) return;

    k_init<<<32, 256, 0, stream>>>(counts, cursors);
    k_cvt <<<(KIN*HC/4+255)/256, 256, 0, stream>>>(W_gat, Wg_bf, KIN*HC/4);
    k_tcvt<<<dim3(NOUT/32, HC/32), 256, 0, stream>>>(W_lin, Wl_t, HC, NOUT);
    // WcT[o][h*128+k] = sum_c Wl_t[o][h*512+c] * Wg_bf[k][h*512+c]
    // A = Wl_t (M=512 rows o, lda=HC, z-off 512); BT = Wg_bf (N=128 rows k, ldb=HC, z-off 512)
    // C = WcT (ldc=YW, z-off 128)
    k_gemm_g<bf16,false><<<dim3(4, 1, NH), 256, 0, stream>>>(
        Wl_t, Wg_bf, nullptr, WcT, NOUT, KIN, OC, HC, HC, YW, OC, OC, KIN);
    k_vsrc<<<KIN, 512, 0, stream>>>(W_gat, att_src, att_dst, v);
    k_attn2<<<(NN*16+255)/256, 256, 0, stream>>>(x, v, a_src, a_dst);
    k_count<<<(NE2+255)/256, 256, 0, stream>>>(eidx, counts);
    k_scan<<<1, 256, 0, stream>>>(counts, offs);
    k_fill<<<(NE2+255)/256, 256, 0, stream>>>(eidx, offs, cursors, esrc);
    k_maxsum<<<(NN*NH+255)/256, 256, 0, stream>>>(offs, esrc, a_src, a_dst, nmax, ninv);
    k_aggx<<<NN/4, 256, 0, stream>>>(offs, esrc, a_src, a_dst, nmax, ninv, x, Ybuf);
    k_beff<<<NOUT/8, 512, 0, stream>>>(b_gat, Wl_t, b_lin, b_eff);
    // out = Y @ Wc + b_eff : M=8000, N=512, K=1024
    k_gemm_g<float,true><<<dim3(63, NOUT/128, 1), 256, 0, stream>>>(
        Ybuf, WcT, b_eff, out, NN, NOUT, YW, YW, YW, NOUT, 0, 0, 0);
}

// Round 8
// 174.525 us; speedup vs baseline: 5.1706x; 1.0566x over previous
//
#include <hip/hip_runtime.h>
#include <hip/hip_bf16.h>
#include <type_traits>

#define NN   8000
#define NE   64000
#define NE2  72000   // edges + self loops
#define NH   8
#define OC   512
#define HC   4096    // NH*OC
#define KIN  128
#define NOUT 512
#define YW   1024    // NH*KIN
#define NEG_SLOPE 0.2f

using bf16 = __hip_bfloat16;
typedef float  f32x4  __attribute__((ext_vector_type(4)));
typedef __bf16 bf16x8 __attribute__((ext_vector_type(8)));

static __device__ __forceinline__ void gld_lds16(const bf16* g, bf16* l){
    __builtin_amdgcn_global_load_lds(
        (const __attribute__((address_space(1))) unsigned int*)g,
        (__attribute__((address_space(3))) unsigned int*)l, 16, 0, 0);
}

// ---------------- transpose+convert: in[K][N] fp32 -> out[N][K] bf16 ----------------
__global__ __launch_bounds__(256) void k_tcvt(const float* __restrict__ in, bf16* __restrict__ out,
                                              int K, int N){
    __shared__ float t[32][33];
    int tx = threadIdx.x & 31, ty = threadIdx.x >> 5;
    int n0 = blockIdx.x*32, k0 = blockIdx.y*32;
    #pragma unroll
    for (int i=0;i<4;++i) t[ty+8*i][tx] = in[(size_t)(k0+ty+8*i)*N + n0+tx];
    __syncthreads();
    #pragma unroll
    for (int i=0;i<4;++i) out[(size_t)(n0+ty+8*i)*K + k0+tx] = __float2bfloat16(t[tx][ty+8*i]);
}

// ---------------- generalized MFMA GEMM (128x128), LDS double-buffered ----------------
// C[row*ldc+col] = sum_k A[row*lda+k] * BT[col*ldb+k]; grid (ceil(M/128), N/128, Z)
template<typename TC, bool BIAS>
__global__ __launch_bounds__(256) void k_gemm_g(
    const bf16* __restrict__ A, const bf16* __restrict__ BT,
    const float* __restrict__ bias, TC* __restrict__ C,
    int M, int N, int K, int lda, int ldb, int ldc,
    int offAz, int offBz, int offCz)
{
    A  += (size_t)blockIdx.z * offAz;
    BT += (size_t)blockIdx.z * offBz;
    C  += (size_t)blockIdx.z * offCz;
    __shared__ __align__(16) bf16 sA[2][128*32];
    __shared__ __align__(16) bf16 sB[2][128*32];
    const int tid  = threadIdx.x;
    const int lane = tid & 63;
    const int w    = tid >> 6;
    const int wm   = w >> 1, wn = w & 1;
    const int m16  = lane & 15, q = lane >> 4;
    const int m0 = blockIdx.x * 128;
    const int n0 = blockIdx.y * 128;

    const int c0 = w*64 + lane;
    const int c1 = 256 + c0;
    const int rA0 = c0 >> 2, kA0 = (c0 & 3) * 8;
    const int rA1 = c1 >> 2, kA1 = (c1 & 3) * 8;
    const size_t gA0 = (size_t)min(m0 + rA0, M-1) * lda + kA0;
    const size_t gA1 = (size_t)min(m0 + rA1, M-1) * lda + kA1;
    const size_t gB0 = (size_t)(n0 + rA0) * ldb + kA0;
    const size_t gB1 = (size_t)(n0 + rA1) * ldb + kA1;

    f32x4 acc[4][4];
    #pragma unroll
    for (int i=0;i<4;++i)
        #pragma unroll
        for (int j=0;j<4;++j)
            #pragma unroll
            for (int r=0;r<4;++r) acc[i][j][r] = 0.f;

    gld_lds16(A  + gA0, sA[0] + c0*8);
    gld_lds16(A  + gA1, sA[0] + c1*8);
    gld_lds16(BT + gB0, sB[0] + c0*8);
    gld_lds16(BT + gB1, sB[0] + c1*8);
    __syncthreads();

    const int nIter = K / 32;
    for (int it = 0; it < nIter; ++it){
        const int cur = it & 1, nxt = cur ^ 1;
        bf16x8 af[4], bfr[4];
        #pragma unroll
        for (int t=0;t<4;++t){
            af[t]  = *(const bf16x8*)(const void*)(sA[cur] + ((wm*64 + t*16 + m16)*32 + q*8));
            bfr[t] = *(const bf16x8*)(const void*)(sB[cur] + ((wn*64 + t*16 + m16)*32 + q*8));
        }
        if (it + 1 < nIter){
            int ko = (it+1) * 32;
            gld_lds16(A  + gA0 + ko, sA[nxt] + c0*8);
            gld_lds16(A  + gA1 + ko, sA[nxt] + c1*8);
            gld_lds16(BT + gB0 + ko, sB[nxt] + c0*8);
            gld_lds16(BT + gB1 + ko, sB[nxt] + c1*8);
        }
        #pragma unroll
        for (int i=0;i<4;++i)
            #pragma unroll
            for (int j=0;j<4;++j)
                acc[i][j] = __builtin_amdgcn_mfma_f32_16x16x32_bf16(af[i], bfr[j], acc[i][j], 0, 0, 0);
        __syncthreads();
    }

    // C/D layout: col = lane&15, row = (lane>>4)*4 + reg
    #pragma unroll
    for (int i=0;i<4;++i){
        int row_base = m0 + wm*64 + i*16 + q*4;
        #pragma unroll
        for (int j=0;j<4;++j){
            int col = n0 + wn*64 + j*16 + m16;
            float bval = BIAS ? bias[col] : 0.f;
            #pragma unroll
            for (int r=0;r<4;++r){
                int row = row_base + r;
                if (row < M){
                    float v = acc[i][j][r] + bval;
                    if constexpr (std::is_same<TC, bf16>::value)
                        C[(size_t)row*ldc + col] = __float2bfloat16(v);
                    else
                        C[(size_t)row*ldc + col] = v;
                }
            }
        }
    }
}

// ---------------- final GEMM: 64x128 tile, M%64==0, higher occupancy ----------------
// out[M][N] fp32 = A[M][K]bf16 @ BT[N][K]^T + bias. grid (M/64, N/128).
__global__ __launch_bounds__(256) void k_gemm64(
    const bf16* __restrict__ A, const bf16* __restrict__ BT,
    const float* __restrict__ bias, float* __restrict__ C,
    int M, int N, int K)
{
    __shared__ __align__(16) bf16 sA[2][64*32];
    __shared__ __align__(16) bf16 sB[2][128*32];
    const int tid  = threadIdx.x;
    const int lane = tid & 63;
    const int w    = tid >> 6;
    const int wm   = w >> 1, wn = w & 1;       // 2x2 wave grid; wave tile 32x64
    const int m16  = lane & 15, q = lane >> 4;
    const int m0 = blockIdx.x * 64;
    const int n0 = blockIdx.y * 128;

    // A: 64 rows x 4 chunks = 256 (1/thread); B: 128 rows x 4 = 512 (2/thread)
    const int rA = tid >> 2,        kA = (tid & 3) * 8;
    const int cB0 = tid, cB1 = 256 + tid;
    const int rB0 = cB0 >> 2, kB0 = (cB0 & 3) * 8;
    const int rB1 = cB1 >> 2, kB1 = (cB1 & 3) * 8;
    const size_t gA  = (size_t)(m0 + rA)  * K + kA;
    const size_t gB0 = (size_t)(n0 + rB0) * K + kB0;
    const size_t gB1 = (size_t)(n0 + rB1) * K + kB1;

    f32x4 acc[2][4];
    #pragma unroll
    for (int i=0;i<2;++i)
        #pragma unroll
        for (int j=0;j<4;++j)
            #pragma unroll
            for (int r=0;r<4;++r) acc[i][j][r] = 0.f;

    gld_lds16(A  + gA,  sA[0] + tid*8);
    gld_lds16(BT + gB0, sB[0] + cB0*8);
    gld_lds16(BT + gB1, sB[0] + cB1*8);
    __syncthreads();

    const int nIter = K / 32;
    for (int it = 0; it < nIter; ++it){
        const int cur = it & 1, nxt = cur ^ 1;
        bf16x8 af[2], bfr[4];
        #pragma unroll
        for (int i=0;i<2;++i)
            af[i]  = *(const bf16x8*)(const void*)(sA[cur] + ((wm*32 + i*16 + m16)*32 + q*8));
        #pragma unroll
        for (int j=0;j<4;++j)
            bfr[j] = *(const bf16x8*)(const void*)(sB[cur] + ((wn*64 + j*16 + m16)*32 + q*8));
        if (it + 1 < nIter){
            int ko = (it+1) * 32;
            gld_lds16(A  + gA  + ko, sA[nxt] + tid*8);
            gld_lds16(BT + gB0 + ko, sB[nxt] + cB0*8);
            gld_lds16(BT + gB1 + ko, sB[nxt] + cB1*8);
        }
        #pragma unroll
        for (int i=0;i<2;++i)
            #pragma unroll
            for (int j=0;j<4;++j)
                acc[i][j] = __builtin_amdgcn_mfma_f32_16x16x32_bf16(af[i], bfr[j], acc[i][j], 0, 0, 0);
        __syncthreads();
    }

    #pragma unroll
    for (int i=0;i<2;++i){
        int row_base = m0 + wm*32 + i*16 + q*4;
        #pragma unroll
        for (int j=0;j<4;++j){
            int col = n0 + wn*64 + j*16 + m16;
            float bval = bias[col];
            #pragma unroll
            for (int r=0;r<4;++r)
                C[(size_t)(row_base + r)*N + col] = acc[i][j][r] + bval;
        }
    }
}

// ---------------- fused: W_gat->bf16 + v[k][o] (o<8: src head, o>=8: dst head) ----------------
__global__ __launch_bounds__(512) void k_vsrc(const float* __restrict__ W_gat,
    const float* __restrict__ att_src, const float* __restrict__ att_dst,
    float* __restrict__ v, bf16* __restrict__ Wg_bf)
{
    int k = blockIdx.x;
    int hh = threadIdx.x >> 6;
    int lane = threadIdx.x & 63;
    const float* wp = W_gat + (size_t)k*HC + hh*OC;
    bf16*        wb = Wg_bf + (size_t)k*HC + hh*OC;
    const float* as = att_src + hh*OC;
    const float* ad = att_dst + hh*OC;
    float ss = 0.f, sd = 0.f;
    #pragma unroll
    for (int c0=0; c0<OC; c0+=64){
        float wv = wp[c0+lane];
        wb[c0+lane] = __float2bfloat16(wv);
        ss += wv * as[c0+lane];
        sd += wv * ad[c0+lane];
    }
    #pragma unroll
    for (int off=32; off; off>>=1){
        ss += __shfl_down(ss, off);
        sd += __shfl_down(sd, off);
    }
    if (lane == 0){
        v[k*16 + hh]     = ss;
        v[k*16 + 8 + hh] = sd;
    }
}

// ---------------- a_src/a_dst [NN][NH] fp32 = x @ v ----------------
__global__ __launch_bounds__(256) void k_attn2(const float* __restrict__ x,
    const float* __restrict__ v, float* __restrict__ a_src, float* __restrict__ a_dst)
{
    int t = blockIdx.x*blockDim.x + threadIdx.x;   // over NN*16
    int node = t >> 4, o = t & 15;
    const float* xp = x + (size_t)node*KIN;
    float acc = 0.f;
    #pragma unroll
    for (int k=0; k<KIN; ++k)
        acc = fmaf(xp[k], v[k*16 + o], acc);
    if (o < 8) a_src[node*NH + o]     = acc;
    else       a_dst[node*NH + o - 8] = acc;
}

// ---------------- CSR build ----------------
__global__ void k_count(const int* __restrict__ eidx, int* __restrict__ counts){
    int e = blockIdx.x*blockDim.x + threadIdx.x;
    if (e >= NE2) return;
    int dst = (e < NE) ? eidx[NE + e] : (e - NE);
    atomicAdd(&counts[dst], 1);
}

__global__ __launch_bounds__(256) void k_scan(const int* __restrict__ counts, int* __restrict__ offsets){
    __shared__ int part[256];
    int t = threadIdx.x;
    int base = t*32;
    int s = 0;
    for (int u=0;u<32;++u){ int i = base+u; if (i<NN) s += counts[i]; }
    part[t] = s;
    __syncthreads();
    for (int off=1; off<256; off<<=1){
        int vv = (t>=off) ? part[t-off] : 0;
        __syncthreads();
        part[t] += vv;
        __syncthreads();
    }
    int run = (t==0) ? 0 : part[t-1];
    for (int u=0;u<32;++u){
        int i = base+u;
        if (i<NN){ offsets[i] = run; run += counts[i]; }
    }
    if (t == 255) offsets[NN] = run;
}

__global__ void k_fill(const int* __restrict__ eidx, const int* __restrict__ offsets,
                       int* __restrict__ cursors, int* __restrict__ esrc){
    int e = blockIdx.x*blockDim.x + threadIdx.x;
    if (e >= NE2) return;
    int src, dst;
    if (e < NE){ src = eidx[e]; dst = eidx[NE+e]; } else { src = dst = e - NE; }
    int pos = atomicAdd(&cursors[dst], 1);
    esrc[offsets[dst] + pos] = src;
}

// ---------------- fused softmax + Y aggregation ----------------
// Y[n][h*128+k] = sum_e alpha[e,h]*x[src_e][k]; wave per node, online max/sum then gather.
__global__ __launch_bounds__(256) void k_aggx(const int* __restrict__ offs,
    const int* __restrict__ esrc, const float* __restrict__ a_src,
    const float* __restrict__ a_dst, const float* __restrict__ x,
    bf16* __restrict__ Y)
{
    int node = blockIdx.x*4 + (threadIdx.x >> 6);
    int lane = threadIdx.x & 63;
    int s0 = offs[node], s1 = offs[node+1];
    float adl = 0.f;
    if (lane < 8) adl = a_dst[node*NH + lane];
    // pass 1: online max/sum on lanes 0..7 (head = lane)
    float m = -1e30f, sum = 0.f;
    for (int s=s0; s<s1; ++s){
        int src = esrc[s];
        if (lane < 8){
            float l = a_src[src*NH + lane] + adl;
            l = l > 0.f ? l : NEG_SLOPE*l;
            float mn = fmaxf(m, l);
            sum = sum*__expf(m - mn) + __expf(l - mn);
            m = mn;
        }
    }
    float inv = 1.f / (sum + 1e-16f);
    // pass 2: weighted gather of x
    float acc[16];
    #pragma unroll
    for (int j=0;j<16;++j) acc[j] = 0.f;
    for (int s=s0; s<s1; ++s){
        int src = esrc[s];
        float wl = 0.f;
        if (lane < 8){
            float l = a_src[src*NH + lane] + adl;
            l = l > 0.f ? l : NEG_SLOPE*l;
            wl = __expf(l - m) * inv;
        }
        float2 xv = *(const float2*)(x + (size_t)src*KIN + lane*2);
        #pragma unroll
        for (int h=0; h<8; ++h){
            float wh = __shfl(wl, h);
            acc[h*2]   = fmaf(wh, xv.x, acc[h*2]);
            acc[h*2+1] = fmaf(wh, xv.y, acc[h*2+1]);
        }
    }
    bf16* yp = Y + (size_t)node*YW + lane*2;
    #pragma unroll
    for (int h=0; h<8; ++h){
        bf16 b0 = __float2bfloat16(acc[h*2]);
        bf16 b1 = __float2bfloat16(acc[h*2+1]);
        ushort2 pk;
        pk.x = *(unsigned short*)&b0;
        pk.y = *(unsigned short*)&b1;
        *reinterpret_cast<ushort2*>(yp + h*KIN) = pk;
    }
}

// ---------------- b_eff[c] = b_lin[c] + b_gat @ Wl_t[c,:] (wave per column) ----------------
__global__ __launch_bounds__(512) void k_beff(const float* __restrict__ b_gat,
    const bf16* __restrict__ Wl_t, const float* __restrict__ b_lin,
    float* __restrict__ b_eff)
{
    int c = blockIdx.x*8 + (threadIdx.x >> 6);
    int lane = threadIdx.x & 63;
    const bf16* wp = Wl_t + (size_t)c*HC;
    float s = 0.f;
    #pragma unroll
    for (int k0=0; k0<HC; k0+=512){
        int k = k0 + lane*8;
        bf16x8 wv = *(const bf16x8*)(const void*)(wp + k);
        float4 g0 = *(const float4*)(b_gat + k);
        float4 g1 = *(const float4*)(b_gat + k + 4);
        s += (float)wv[0]*g0.x + (float)wv[1]*g0.y + (float)wv[2]*g0.z + (float)wv[3]*g0.w
           + (float)wv[4]*g1.x + (float)wv[5]*g1.y + (float)wv[6]*g1.z + (float)wv[7]*g1.w;
    }
    #pragma unroll
    for (int off=32; off; off>>=1) s += __shfl_down(s, off);
    if (lane == 0) b_eff[c] = b_lin[c] + s;
}

extern "C" void kernel_launch(void* const* d_in, const int* in_sizes, int n_in,
                              void* d_out, int out_size, void* d_ws, size_t ws_size,
                              hipStream_t stream)
{
    const float* x       = (const float*)d_in[0];
    const int*   eidx    = (const int*)  d_in[1];
    const float* W_gat   = (const float*)d_in[2];
    const float* b_gat   = (const float*)d_in[3];
    const float* att_src = (const float*)d_in[4];
    const float* att_dst = (const float*)d_in[5];
    const float* W_lin   = (const float*)d_in[6];
    const float* b_lin   = (const float*)d_in[7];
    float* out = (float*)d_out;

    char* p = (char*)d_ws;
    auto alloc = [&](size_t bytes){ void* r = (void*)p; p += (bytes + 255) & ~(size_t)255; return r; };
    bf16*  Wg_bf  = (bf16*) alloc((size_t)KIN*HC*2);      // 1 MB
    bf16*  Wl_t   = (bf16*) alloc((size_t)NOUT*HC*2);     // 4 MB
    bf16*  WcT    = (bf16*) alloc((size_t)NOUT*YW*2);     // 1 MB
    bf16*  Ybuf   = (bf16*) alloc((size_t)NN*YW*2);       // 16.4 MB
    float* v      = (float*)alloc((size_t)KIN*16*4);
    float* a_src  = (float*)alloc((size_t)NN*NH*4);
    float* a_dst  = (float*)alloc((size_t)NN*NH*4);
    int*   offs   = (int*)  alloc((size_t)(NN+1)*4);
    int*   counts = (int*)  alloc((size_t)NN*4);          // NN*4 = 32000, 256-aligned
    int*   cursors= (int*)  alloc((size_t)NN*4);          // contiguous after counts
    int*   esrc   = (int*)  alloc((size_t)NE2*4);
    float* b_eff  = (float*)alloc((size_t)NOUT*4);
    if ((size_t)(p - (char*)d_ws) > ws_size) return;

    hipMemsetAsync(counts, 0, (size_t)2*NN*4, stream);    // counts + cursors (adjacent)
    k_vsrc<<<KIN, 512, 0, stream>>>(W_gat, att_src, att_dst, v, Wg_bf);
    k_tcvt<<<dim3(NOUT/32, HC/32), 256, 0, stream>>>(W_lin, Wl_t, HC, NOUT);
    // WcT[o][h*128+k] = sum_c Wl_t[o][h*512+c] * Wg_bf[k][h*512+c]  (per-head z)
    k_gemm_g<bf16,false><<<dim3(4, 1, NH), 256, 0, stream>>>(
        Wl_t, Wg_bf, nullptr, WcT, NOUT, KIN, OC, HC, HC, YW, OC, OC, KIN);
    k_attn2<<<(NN*16+255)/256, 256, 0, stream>>>(x, v, a_src, a_dst);
    k_count<<<(NE2+255)/256, 256, 0, stream>>>(eidx, counts);
    k_scan<<<1, 256, 0, stream>>>(counts, offs);
    k_fill<<<(NE2+255)/256, 256, 0, stream>>>(eidx, offs, cursors, esrc);
    k_aggx<<<NN/4, 256, 0, stream>>>(offs, esrc, a_src, a_dst, x, Ybuf);
    k_beff<<<NOUT/8, 512, 0, stream>>>(b_gat, Wl_t, b_lin, b_eff);
    // out = Y @ Wc + b_eff : M=8000 (64-mult), N=512, K=1024
    k_gemm64<<<dim3(NN/64, NOUT/128), 256, 0, stream>>>(Ybuf, WcT, b_eff, out, NN, NOUT, YW);
}

// Round 10
// 151.293 us; speedup vs baseline: 5.9645x; 1.1536x over previous
//
#include <hip/hip_runtime.h>
#include <hip/hip_bf16.h>
#include <type_traits>

#define NN   8000
#define NE   64000
#define NE2  72000   // edges + self loops
#define NH   8
#define OC   512
#define HC   4096    // NH*OC
#define KIN  128
#define NOUT 512
#define YW   1024    // NH*KIN
#define NEG_SLOPE 0.2f
#define WCSK 4       // split-K planes for Wc GEMM

using bf16 = __hip_bfloat16;
typedef float  f32x4  __attribute__((ext_vector_type(4)));
typedef __bf16 bf16x8 __attribute__((ext_vector_type(8)));

static __device__ __forceinline__ void gld_lds16(const bf16* g, bf16* l){
    __builtin_amdgcn_global_load_lds(
        (const __attribute__((address_space(1))) unsigned int*)g,
        (__attribute__((address_space(3))) unsigned int*)l, 16, 0, 0);
}

// ================= phase A: independent preprocessing =================
// blocks [0,2048): W_lin transpose->bf16 + b_eff column partials (atomicAdd)
// blocks [2048,2176): W_gat->bf16 + v[k][o] attention vectors
// blocks [2176,2458): edge dst counting
// NOTE: no block in this grid reads another block's output (G16).
#define TCVT_NB   2048
#define VSRC_BASE 2048
#define CNT_BASE  2176
#define PHA_NB    2458

__global__ __launch_bounds__(256) void k_phaseA(
    const float* __restrict__ W_lin, const float* __restrict__ b_gat,
    const float* __restrict__ W_gat,
    const float* __restrict__ att_src, const float* __restrict__ att_dst,
    const int* __restrict__ eidx,
    bf16* __restrict__ Wl_t, float* __restrict__ b_eff,
    bf16* __restrict__ Wg_bf, float* __restrict__ v,
    int* __restrict__ counts)
{
    __shared__ __align__(16) float smem[32*33 + 32];
    const int bid = blockIdx.x;
    const int tid = threadIdx.x;

    if (bid < TCVT_NB){
        // ---- W_lin[4096][512] -> Wl_t[512][4096] bf16 ; b_eff partials ----
        float (*t)[33] = (float(*)[33])smem;
        float* bpart = smem + 32*33;
        if (tid < 32) bpart[tid] = 0.f;
        __syncthreads();
        int tx = tid & 31, ty = tid >> 5;
        int n0 = (bid & 15) * 32, k0 = (bid >> 4) * 32;
        float pb = 0.f;
        #pragma unroll
        for (int i=0;i<4;++i){
            int k = k0 + ty + 8*i;
            float val = W_lin[(size_t)k*NOUT + n0 + tx];
            t[ty+8*i][tx] = val;
            pb = fmaf(b_gat[k], val, pb);
        }
        atomicAdd(&bpart[tx], pb);
        __syncthreads();
        #pragma unroll
        for (int i=0;i<4;++i)
            Wl_t[(size_t)(n0+ty+8*i)*HC + k0+tx] = __float2bfloat16(t[tx][ty+8*i]);
        if (tid < 32) atomicAdd(b_eff + n0 + tid, bpart[tid]);
    } else if (bid < CNT_BASE){
        // ---- W_gat row k -> bf16 + v[k][o] ----
        int k = bid - VSRC_BASE;
        int lane = tid & 63, g = tid >> 6;           // 4 wave-groups, 2 heads each
        for (int hh = g; hh < NH; hh += 4){
            const float* wp = W_gat + (size_t)k*HC + hh*OC;
            bf16*        wb = Wg_bf + (size_t)k*HC + hh*OC;
            const float* as = att_src + hh*OC;
            const float* ad = att_dst + hh*OC;
            float ss = 0.f, sd = 0.f;
            #pragma unroll
            for (int c0=0; c0<OC; c0+=64){
                float wv = wp[c0+lane];
                wb[c0+lane] = __float2bfloat16(wv);
                ss = fmaf(wv, as[c0+lane], ss);
                sd = fmaf(wv, ad[c0+lane], sd);
            }
            #pragma unroll
            for (int off=32; off; off>>=1){
                ss += __shfl_down(ss, off);
                sd += __shfl_down(sd, off);
            }
            if (lane == 0){
                v[k*16 + hh]     = ss;
                v[k*16 + 8 + hh] = sd;
            }
        }
    } else {
        // ---- count edge destinations ----
        int e = (bid - CNT_BASE)*256 + tid;
        if (e < NE2){
            int dst = (e < NE) ? eidx[NE + e] : (e - NE);
            atomicAdd(&counts[dst], 1);
        }
    }
}

// ================= phase B: Wc split-K GEMM (128 blocks) + CSR scan (1 block) ========
// wc: bid<128: m-tile = bid&3, z = bid>>2, head = z/WCSK, sp = z%WCSK
// partW[sp][o][h*128+k] = sum_{c in sp-chunk} Wl_t[o][h*512+c]*Wg_bf[k][h*512+c]
__global__ __launch_bounds__(256) void k_phaseB(
    const bf16* __restrict__ Wl_t, const bf16* __restrict__ Wg_bf,
    float* __restrict__ partW,
    const int* __restrict__ counts, int* __restrict__ offsets)
{
    __shared__ __align__(16) bf16 sA[2][128*32];
    __shared__ __align__(16) bf16 sB[2][128*32];
    __shared__ int part[256];
    const int bid = blockIdx.x;
    const int tid = threadIdx.x;

    if (bid == 128){
        // ---- prefix scan counts -> offsets ----
        int t = tid;
        int base = t*32;
        int s = 0;
        for (int u=0;u<32;++u){ int i = base+u; if (i<NN) s += counts[i]; }
        part[t] = s;
        __syncthreads();
        for (int off=1; off<256; off<<=1){
            int vv = (t>=off) ? part[t-off] : 0;
            __syncthreads();
            part[t] += vv;
            __syncthreads();
        }
        int run = (t==0) ? 0 : part[t-1];
        for (int u=0;u<32;++u){
            int i = base+u;
            if (i<NN){ offsets[i] = run; run += counts[i]; }
        }
        if (t == 255) offsets[NN] = run;
        return;
    }

    const int head = (bid >> 2) / WCSK;
    const int sp   = (bid >> 2) % WCSK;
    const bf16* A  = Wl_t  + head*OC + sp*128;
    const bf16* BT = Wg_bf + head*OC + sp*128;
    const int lane = tid & 63;
    const int w    = tid >> 6;
    const int wm   = w >> 1, wn = w & 1;
    const int m16  = lane & 15, q = lane >> 4;
    const int m0 = (bid & 3) * 128;

    const int c0 = w*64 + lane;
    const int c1 = 256 + c0;
    const int rA0 = c0 >> 2, kA0 = (c0 & 3) * 8;
    const int rA1 = c1 >> 2, kA1 = (c1 & 3) * 8;
    const size_t gA0 = (size_t)(m0 + rA0) * HC + kA0;
    const size_t gA1 = (size_t)(m0 + rA1) * HC + kA1;
    const size_t gB0 = (size_t)rA0 * HC + kA0;
    const size_t gB1 = (size_t)rA1 * HC + kA1;

    f32x4 acc[4][4];
    #pragma unroll
    for (int i=0;i<4;++i)
        #pragma unroll
        for (int j=0;j<4;++j)
            #pragma unroll
            for (int r=0;r<4;++r) acc[i][j][r] = 0.f;

    gld_lds16(A  + gA0, sA[0] + c0*8);
    gld_lds16(A  + gA1, sA[0] + c1*8);
    gld_lds16(BT + gB0, sB[0] + c0*8);
    gld_lds16(BT + gB1, sB[0] + c1*8);
    __syncthreads();

    #pragma unroll
    for (int it = 0; it < 4; ++it){
        const int cur = it & 1, nxt = cur ^ 1;
        bf16x8 af[4], bfr[4];
        #pragma unroll
        for (int t=0;t<4;++t){
            af[t]  = *(const bf16x8*)(const void*)(sA[cur] + ((wm*64 + t*16 + m16)*32 + q*8));
            bfr[t] = *(const bf16x8*)(const void*)(sB[cur] + ((wn*64 + t*16 + m16)*32 + q*8));
        }
        if (it + 1 < 4){
            int ko = (it+1) * 32;
            gld_lds16(A  + gA0 + ko, sA[nxt] + c0*8);
            gld_lds16(A  + gA1 + ko, sA[nxt] + c1*8);
            gld_lds16(BT + gB0 + ko, sB[nxt] + c0*8);
            gld_lds16(BT + gB1 + ko, sB[nxt] + c1*8);
        }
        #pragma unroll
        for (int i=0;i<4;++i)
            #pragma unroll
            for (int j=0;j<4;++j)
                acc[i][j] = __builtin_amdgcn_mfma_f32_16x16x32_bf16(af[i], bfr[j], acc[i][j], 0, 0, 0);
        __syncthreads();
    }

    float* pout = partW + (size_t)sp*NOUT*YW + head*KIN;
    #pragma unroll
    for (int i=0;i<4;++i){
        int row_base = m0 + wm*64 + i*16 + q*4;
        #pragma unroll
        for (int j=0;j<4;++j){
            int col = wn*64 + j*16 + m16;
            #pragma unroll
            for (int r=0;r<4;++r)
                pout[(size_t)(row_base + r)*YW + col] = acc[i][j][r];
        }
    }
}

// ================= phase C: CSR fill (282 blocks) + attn2 (500 blocks) =================
#define FILL_NB 282
#define PHC_NB  782

__global__ __launch_bounds__(256) void k_phaseC(
    const int* __restrict__ eidx, const int* __restrict__ offsets,
    int* __restrict__ cursors, int* __restrict__ esrc,
    const float* __restrict__ x, const float* __restrict__ v,
    float* __restrict__ a_src, float* __restrict__ a_dst)
{
    __shared__ __align__(16) float smem[16*132*2];
    const int bid = blockIdx.x;
    const int tid = threadIdx.x;

    if (bid < FILL_NB){
        int e = bid*256 + tid;
        if (e < NE2){
            int src, dst;
            if (e < NE){ src = eidx[e]; dst = eidx[NE+e]; } else { src = dst = e - NE; }
            int pos = atomicAdd(&cursors[dst], 1);
            esrc[offsets[dst] + pos] = src;
        }
        return;
    }
    // ---- a_src/a_dst = x @ v, 16 nodes per block, LDS-staged ----
    float (*xs)[132] = (float(*)[132])smem;
    float (*vt)[132] = (float(*)[132])(smem + 16*132);
    int node0 = (bid - FILL_NB) * 16;
    {
        const float* xg = x + (size_t)node0*KIN;
        int row = tid >> 4, co = (tid & 15) * 8;
        float4 v0 = *(const float4*)(xg + row*KIN + co);
        float4 v1 = *(const float4*)(xg + row*KIN + co + 4);
        *(float4*)&xs[row][co]     = v0;
        *(float4*)&xs[row][co + 4] = v1;
    }
    {
        int base = tid*8;
        #pragma unroll
        for (int j=0;j<8;++j){
            int idx = base + j;
            vt[idx & 15][idx >> 4] = v[idx];
        }
    }
    __syncthreads();
    int ln = tid >> 4, o = tid & 15;
    float acc = 0.f;
    #pragma unroll
    for (int k0=0;k0<KIN;k0+=4){
        float4 xv = *(const float4*)&xs[ln][k0];
        float4 vv = *(const float4*)&vt[o][k0];
        acc += xv.x*vv.x + xv.y*vv.y + xv.z*vv.z + xv.w*vv.w;
    }
    int node = node0 + ln;
    if (o < 8) a_src[node*NH + o]     = acc;
    else       a_dst[node*NH + o - 8] = acc;
}

// ================= fused: Y aggregation (blocks<2000) + Wc partial reduce =================
__global__ __launch_bounds__(256) void k_aggxr(const int* __restrict__ offs,
    const int* __restrict__ esrc, const float* __restrict__ a_src,
    const float* __restrict__ a_dst, const float* __restrict__ x,
    const float* __restrict__ partW, bf16* __restrict__ Y, bf16* __restrict__ WcT)
{
    int bid = blockIdx.x;
    int tid = threadIdx.x;
    if (bid >= NN/4){
        // ---- reduce partW -> WcT bf16 : 512*1024 elems, 8/thread ----
        int t = (bid - NN/4)*256 + tid;
        int base = t*8;
        float s[8];
        #pragma unroll
        for (int j=0;j<8;++j) s[j] = 0.f;
        #pragma unroll
        for (int sp=0; sp<WCSK; ++sp){
            const float4* pp = (const float4*)(partW + (size_t)sp*NOUT*YW + base);
            float4 p0 = pp[0], p1 = pp[1];
            s[0]+=p0.x; s[1]+=p0.y; s[2]+=p0.z; s[3]+=p0.w;
            s[4]+=p1.x; s[5]+=p1.y; s[6]+=p1.z; s[7]+=p1.w;
        }
        bf16x8 o;
        #pragma unroll
        for (int j=0;j<8;++j) o[j] = (__bf16)s[j];
        *(bf16x8*)(void*)(WcT + base) = o;
        return;
    }
    // ---- Y[n][h*128+k] = sum_e alpha[e,h]*x[src_e][k] ; wave per node ----
    int node = bid*4 + (tid >> 6);
    int lane = tid & 63;
    int s0 = offs[node], s1 = offs[node+1];
    int g = lane >> 3, h = lane & 7;
    float adl = a_dst[node*NH + h];
    // parallel online max/sum: 8 edge-groups x 8 heads
    float m = -1e30f, sum = 0.f;
    for (int e = s0 + g; e < s1; e += 8){
        float l = a_src[esrc[e]*NH + h] + adl;
        l = l > 0.f ? l : NEG_SLOPE*l;
        float mn = fmaxf(m, l);
        sum = sum*__expf(m - mn) + __expf(l - mn);
        m = mn;
    }
    #pragma unroll
    for (int d=8; d<64; d<<=1){
        float mo = __shfl_xor(m, d);
        float so = __shfl_xor(sum, d);
        float mn = fmaxf(m, mo);
        sum = sum*__expf(m - mn) + so*__expf(mo - mn);
        m = mn;
    }
    float inv = 1.f / (sum + 1e-16f);
    float acc[16];
    #pragma unroll
    for (int j=0;j<16;++j) acc[j] = 0.f;
    for (int s=s0; s<s1; ++s){
        int src = esrc[s];
        float wl = 0.f;
        if (lane < 8){
            float l = a_src[src*NH + lane] + adl;
            l = l > 0.f ? l : NEG_SLOPE*l;
            wl = __expf(l - m) * inv;
        }
        float2 xv = *(const float2*)(x + (size_t)src*KIN + lane*2);
        #pragma unroll
        for (int hh=0; hh<8; ++hh){
            float wh = __shfl(wl, hh);
            acc[hh*2]   = fmaf(wh, xv.x, acc[hh*2]);
            acc[hh*2+1] = fmaf(wh, xv.y, acc[hh*2+1]);
        }
    }
    bf16* yp = Y + (size_t)node*YW + lane*2;
    #pragma unroll
    for (int hh=0; hh<8; ++hh){
        bf16 b0 = __float2bfloat16(acc[hh*2]);
        bf16 b1 = __float2bfloat16(acc[hh*2+1]);
        ushort2 pk;
        pk.x = *(unsigned short*)&b0;
        pk.y = *(unsigned short*)&b1;
        *reinterpret_cast<ushort2*>(yp + hh*KIN) = pk;
    }
}

// ================= final GEMM: out = Y @ WcT^T + b_eff + b_lin (64x128 tile) =================
__global__ __launch_bounds__(256) void k_gemm64(
    const bf16* __restrict__ A, const bf16* __restrict__ BT,
    const float* __restrict__ b_eff, const float* __restrict__ b_lin,
    float* __restrict__ C, int M, int N, int K)
{
    __shared__ __align__(16) bf16 sA[2][64*32];
    __shared__ __align__(16) bf16 sB[2][128*32];
    const int tid  = threadIdx.x;
    const int lane = tid & 63;
    const int w    = tid >> 6;
    const int wm   = w >> 1, wn = w & 1;       // wave tile 32x64
    const int m16  = lane & 15, q = lane >> 4;
    const int m0 = blockIdx.x * 64;
    const int n0 = blockIdx.y * 128;

    const int rA = tid >> 2,  kA = (tid & 3) * 8;
    const int cB0 = tid, cB1 = 256 + tid;
    const int rB0 = cB0 >> 2, kB0 = (cB0 & 3) * 8;
    const int rB1 = cB1 >> 2, kB1 = (cB1 & 3) * 8;
    const size_t gA  = (size_t)(m0 + rA)  * K + kA;
    const size_t gB0 = (size_t)(n0 + rB0) * K + kB0;
    const size_t gB1 = (size_t)(n0 + rB1) * K + kB1;

    f32x4 acc[2][4];
    #pragma unroll
    for (int i=0;i<2;++i)
        #pragma unroll
        for (int j=0;j<4;++j)
            #pragma unroll
            for (int r=0;r<4;++r) acc[i][j][r] = 0.f;

    gld_lds16(A  + gA,  sA[0] + tid*8);
    gld_lds16(BT + gB0, sB[0] + cB0*8);
    gld_lds16(BT + gB1, sB[0] + cB1*8);
    __syncthreads();

    const int nIter = K / 32;
    for (int it = 0; it < nIter; ++it){
        const int cur = it & 1, nxt = cur ^ 1;
        bf16x8 af[2], bfr[4];
        #pragma unroll
        for (int i=0;i<2;++i)
            af[i]  = *(const bf16x8*)(const void*)(sA[cur] + ((wm*32 + i*16 + m16)*32 + q*8));
        #pragma unroll
        for (int j=0;j<4;++j)
            bfr[j] = *(const bf16x8*)(const void*)(sB[cur] + ((wn*64 + j*16 + m16)*32 + q*8));
        if (it + 1 < nIter){
            int ko = (it+1) * 32;
            gld_lds16(A  + gA  + ko, sA[nxt] + tid*8);
            gld_lds16(BT + gB0 + ko, sB[nxt] + cB0*8);
            gld_lds16(BT + gB1 + ko, sB[nxt] + cB1*8);
        }
        #pragma unroll
        for (int i=0;i<2;++i)
            #pragma unroll
            for (int j=0;j<4;++j)
                acc[i][j] = __builtin_amdgcn_mfma_f32_16x16x32_bf16(af[i], bfr[j], acc[i][j], 0, 0, 0);
        __syncthreads();
    }

    #pragma unroll
    for (int i=0;i<2;++i){
        int row_base = m0 + wm*32 + i*16 + q*4;
        #pragma unroll
        for (int j=0;j<4;++j){
            int col = n0 + wn*64 + j*16 + m16;
            float bval = b_eff[col] + b_lin[col];
            #pragma unroll
            for (int r=0;r<4;++r)
                C[(size_t)(row_base + r)*N + col] = acc[i][j][r] + bval;
        }
    }
}

extern "C" void kernel_launch(void* const* d_in, const int* in_sizes, int n_in,
                              void* d_out, int out_size, void* d_ws, size_t ws_size,
                              hipStream_t stream)
{
    const float* x       = (const float*)d_in[0];
    const int*   eidx    = (const int*)  d_in[1];
    const float* W_gat   = (const float*)d_in[2];
    const float* b_gat   = (const float*)d_in[3];
    const float* att_src = (const float*)d_in[4];
    const float* att_dst = (const float*)d_in[5];
    const float* W_lin   = (const float*)d_in[6];
    const float* b_lin   = (const float*)d_in[7];
    float* out = (float*)d_out;

    char* p = (char*)d_ws;
    auto alloc = [&](size_t bytes){ void* r = (void*)p; p += (bytes + 255) & ~(size_t)255; return r; };
    bf16*  Wg_bf  = (bf16*) alloc((size_t)KIN*HC*2);        // 1 MB
    bf16*  Wl_t   = (bf16*) alloc((size_t)NOUT*HC*2);       // 4 MB
    bf16*  WcT    = (bf16*) alloc((size_t)NOUT*YW*2);       // 1 MB
    bf16*  Ybuf   = (bf16*) alloc((size_t)NN*YW*2);         // 16.4 MB
    float* partW  = (float*)alloc((size_t)WCSK*NOUT*YW*4);  // 8.4 MB
    float* v      = (float*)alloc((size_t)KIN*16*4);
    float* a_src  = (float*)alloc((size_t)NN*NH*4);
    float* a_dst  = (float*)alloc((size_t)NN*NH*4);
    int*   offs   = (int*)  alloc((size_t)(NN+1)*4);
    int*   esrc   = (int*)  alloc((size_t)NE2*4);
    // zero-init group (contiguous)
    int*   counts = (int*)  alloc((size_t)NN*4);
    int*   cursors= (int*)  alloc((size_t)NN*4);
    float* b_eff  = (float*)alloc((size_t)NOUT*4);
    if ((size_t)(p - (char*)d_ws) > ws_size) return;

    hipMemsetAsync(counts, 0, (size_t)2*NN*4 + NOUT*4, stream);  // counts+cursors+b_eff
    k_phaseA<<<PHA_NB, 256, 0, stream>>>(W_lin, b_gat, W_gat, att_src, att_dst,
                                         eidx, Wl_t, b_eff, Wg_bf, v, counts);
    k_phaseB<<<129, 256, 0, stream>>>(Wl_t, Wg_bf, partW, counts, offs);
    k_phaseC<<<PHC_NB, 256, 0, stream>>>(eidx, offs, cursors, esrc, x, v, a_src, a_dst);
    k_aggxr<<<NN/4 + NOUT*YW/(8*256), 256, 0, stream>>>(offs, esrc, a_src, a_dst,
                                                        x, partW, Ybuf, WcT);
    k_gemm64<<<dim3(NN/64, NOUT/128), 256, 0, stream>>>(Ybuf, WcT, b_eff, b_lin,
                                                        out, NN, NOUT, YW);
}